// Round 6
// baseline (142.675 us; speedup 1.0000x reference)
//
#include <hip/hip_runtime.h>
#include <hip/hip_bf16.h>
#include <cstddef>
#include <cstdint>

#define BB    8
#define TT    2048
#define KIN   1024
#define NOUT  512
#define CHUNK 32
#define NCHUNK (TT / CHUNK)   // 64

#define BM 128
#define BN 64
#define BK 64
#define NKSTEP (KIN / BK)     // 16

typedef __attribute__((ext_vector_type(4))) float          f32x4;
typedef __attribute__((ext_vector_type(4))) unsigned int   u32x4;
typedef _Float16 f16x8 __attribute__((ext_vector_type(8)));

// ---------------------------------------------------------------------------
// W f32 -> fp16 (RNE).  1 MB output, trivial pass.
// ---------------------------------------------------------------------------
__global__ __launch_bounds__(256) void conv_f16_kernel(
    const float* __restrict__ src, _Float16* __restrict__ dst, int n8) {
  int i = blockIdx.x * blockDim.x + threadIdx.x;
  const int stride = gridDim.x * blockDim.x;
  for (; i < n8; i += stride) {
    float4 x0 = reinterpret_cast<const float4*>(src)[2 * i];
    float4 x1 = reinterpret_cast<const float4*>(src)[2 * i + 1];
    f16x8 h;
    h[0] = (_Float16)x0.x; h[1] = (_Float16)x0.y;
    h[2] = (_Float16)x0.z; h[3] = (_Float16)x0.w;
    h[4] = (_Float16)x1.x; h[5] = (_Float16)x1.y;
    h[6] = (_Float16)x1.z; h[7] = (_Float16)x1.w;
    reinterpret_cast<f16x8*>(dst)[i] = h;
  }
}

// ---------------------------------------------------------------------------
// fp16 MFMA GEMM, pipelined:
//  - A (X, f32) reg-staged: global->VGPR (issued for t+1 at top of iter t),
//    cvt_pkrtz -> f16, ds_write_b128 with slot^=(row&7) swizzle (both sides).
//  - A LDS double-buffered: 2 x 128x64 f16 = 32KB; ONE barrier per K-step.
//  - B (W, f16, L2-resident) loaded per-fragment straight to registers.
//  - 16 K-steps (BK=64), 16 MFMA (16x16x32 f16) per wave per step.
// grid = (128 m-strips, 8 n-tiles) = 1024 blocks = 4/CU resident;
// y-stride 128 == 0 mod 8 -> all 8 n-blocks of an m-strip on one XCD.
// ---------------------------------------------------------------------------
__global__ __launch_bounds__(256, 4) void gemm_f16(
    const float* __restrict__ X, const _Float16* __restrict__ Wh,
    const float* __restrict__ bias, float* __restrict__ C) {
  __shared__ __align__(16) unsigned char smem[2 * 16384];  // A dbuf only

  const int tid  = threadIdx.x;
  const int wave = tid >> 6;
  const int lane = tid & 63;
  const int m0 = blockIdx.x * BM;
  const int n0 = blockIdx.y * BN;
  const int wm = (wave >> 1) * 64;   // 2x2 waves: 64x32 output each
  const int wn = (wave & 1) * 32;

  // --- A staging (reg-staged): thread covers row=tid>>1, slots (tid&1)*4+s ---
  const int arow  = tid >> 1;               // 0..127
  const int asl0  = (tid & 1) << 2;         // 0 or 4 (slot base, 8 f16 each)
  const float* pA = X + (size_t)(m0 + arow) * KIN + asl0 * 8;
  // ds_write byte offsets (swizzled), one per segment s
  int wb[4];
#pragma unroll
  for (int s = 0; s < 4; ++s)
    wb[s] = arow * 128 + (((asl0 + s) ^ (arow & 7)) << 4);

  // --- A fragment-read swizzled slot offsets (per lane, per kk) ---
  const int oA0 = (((lane >> 4))     ^ (lane & 7)) << 4;   // kk=0: slot 0..3
  const int oA1 = ((4 + (lane >> 4)) ^ (lane & 7)) << 4;   // kk=1: slot 4..7

  // --- B fragment base: row = n0+wn+ni*16+(lane&15), k-gp = (lane>>4)*8 ---
  const _Float16* pB = Wh + (size_t)(n0 + wn + (lane & 15)) * KIN + ((lane >> 4) << 3);

  f32x4 acc[4][2] = {};
  f32x4 ra[4][2];

  // prologue: load tile 0, cvt, write to buf 0
#pragma unroll
  for (int s = 0; s < 4; ++s) {
    ra[s][0] = *reinterpret_cast<const f32x4*>(pA + s * 8);
    ra[s][1] = *reinterpret_cast<const f32x4*>(pA + s * 8 + 4);
  }
#pragma unroll
  for (int s = 0; s < 4; ++s) {
    u32x4 hv;
    hv[0] = __builtin_bit_cast(unsigned int, __builtin_amdgcn_cvt_pkrtz(ra[s][0][0], ra[s][0][1]));
    hv[1] = __builtin_bit_cast(unsigned int, __builtin_amdgcn_cvt_pkrtz(ra[s][0][2], ra[s][0][3]));
    hv[2] = __builtin_bit_cast(unsigned int, __builtin_amdgcn_cvt_pkrtz(ra[s][1][0], ra[s][1][1]));
    hv[3] = __builtin_bit_cast(unsigned int, __builtin_amdgcn_cvt_pkrtz(ra[s][1][2], ra[s][1][3]));
    *reinterpret_cast<u32x4*>(smem + wb[s]) = hv;
  }
  __syncthreads();

  for (int t = 0; t < NKSTEP; ++t) {
    const unsigned char* bufA = smem + (t & 1) * 16384;
    unsigned char*       nxtA = smem + ((t + 1) & 1) * 16384;

    // issue A global loads for t+1 (fly under this iter's compute)
    if (t + 1 < NKSTEP) {
      const int k0 = (t + 1) * BK;
#pragma unroll
      for (int s = 0; s < 4; ++s) {
        ra[s][0] = *reinterpret_cast<const f32x4*>(pA + k0 + s * 8);
        ra[s][1] = *reinterpret_cast<const f32x4*>(pA + k0 + s * 8 + 4);
      }
    }

    // B fragments for this iter: straight from global (L2-resident W)
    f16x8 bf[2][2];
#pragma unroll
    for (int ni = 0; ni < 2; ++ni)
#pragma unroll
      for (int kk = 0; kk < 2; ++kk)
        bf[ni][kk] = *reinterpret_cast<const f16x8*>(pB + (size_t)ni * 16 * KIN + t * BK + kk * 32);

    // A fragments from LDS (swizzled), then MFMA
    f16x8 af[4][2];
#pragma unroll
    for (int mi = 0; mi < 4; ++mi) {
      const int rb = (wm + mi * 16 + (lane & 15)) * 128;
      af[mi][0] = *reinterpret_cast<const f16x8*>(bufA + rb + oA0);
      af[mi][1] = *reinterpret_cast<const f16x8*>(bufA + rb + oA1);
    }
#pragma unroll
    for (int kk = 0; kk < 2; ++kk)
#pragma unroll
      for (int ni = 0; ni < 2; ++ni)
#pragma unroll
        for (int mi = 0; mi < 4; ++mi)
          acc[mi][ni] = __builtin_amdgcn_mfma_f32_16x16x32_f16(af[mi][kk], bf[ni][kk], acc[mi][ni], 0, 0, 0);

    // cvt + write staged tile t+1 into the other buffer, then barrier
    if (t + 1 < NKSTEP) {
#pragma unroll
      for (int s = 0; s < 4; ++s) {
        u32x4 hv;
        hv[0] = __builtin_bit_cast(unsigned int, __builtin_amdgcn_cvt_pkrtz(ra[s][0][0], ra[s][0][1]));
        hv[1] = __builtin_bit_cast(unsigned int, __builtin_amdgcn_cvt_pkrtz(ra[s][0][2], ra[s][0][3]));
        hv[2] = __builtin_bit_cast(unsigned int, __builtin_amdgcn_cvt_pkrtz(ra[s][1][0], ra[s][1][1]));
        hv[3] = __builtin_bit_cast(unsigned int, __builtin_amdgcn_cvt_pkrtz(ra[s][1][2], ra[s][1][3]));
        *reinterpret_cast<u32x4*>(nxtA + wb[s]) = hv;
      }
      __syncthreads();
    }
  }

  // epilogue: C/D layout col = lane&15, row = (lane>>4)*4 + r  [m89-verified]
  const int colb = n0 + wn + (lane & 15);
  const int rowb = m0 + wm + ((lane >> 4) << 2);
#pragma unroll
  for (int ni = 0; ni < 2; ++ni) {
    const float bv = bias[colb + ni * 16];
#pragma unroll
    for (int mi = 0; mi < 4; ++mi) {
#pragma unroll
      for (int r = 0; r < 4; ++r) {
        C[(size_t)(rowb + mi * 16 + r) * NOUT + colb + ni * 16] = acc[mi][ni][r] + bv;
      }
    }
  }
}

// ---------------------------------------------------------------------------
// Fallback f32 GEMM (verified R1) — only if workspace is too small.
// ---------------------------------------------------------------------------
__global__ __launch_bounds__(256) void gemm_f32_64x64(
    const float* __restrict__ X, const float* __restrict__ W,
    const float* __restrict__ bias, float* __restrict__ C) {
  __shared__ float As[16][65];
  __shared__ float Bs[16][65];
  const int m0  = blockIdx.y * 64;
  const int n0  = blockIdx.x * 64;
  const int tid = threadIdx.x;
  const int tx  = tid & 15;
  const int ty  = tid >> 4;
  const int lr  = tid >> 2;
  const int lk  = (tid & 3) << 2;
  float acc[4][4] = {};
  const float* xa = X + (size_t)(m0 + lr) * KIN + lk;
  const float* wb = W + (size_t)(n0 + lr) * KIN + lk;
  for (int k0 = 0; k0 < KIN; k0 += 16) {
    float4 av = *reinterpret_cast<const float4*>(xa + k0);
    float4 bv = *reinterpret_cast<const float4*>(wb + k0);
    As[lk + 0][lr] = av.x; As[lk + 1][lr] = av.y;
    As[lk + 2][lr] = av.z; As[lk + 3][lr] = av.w;
    Bs[lk + 0][lr] = bv.x; Bs[lk + 1][lr] = bv.y;
    Bs[lk + 2][lr] = bv.z; Bs[lk + 3][lr] = bv.w;
    __syncthreads();
#pragma unroll
    for (int k = 0; k < 16; ++k) {
      float a[4], b[4];
#pragma unroll
      for (int i = 0; i < 4; ++i) a[i] = As[k][ty * 4 + i];
#pragma unroll
      for (int j = 0; j < 4; ++j) b[j] = Bs[k][tx * 4 + j];
#pragma unroll
      for (int i = 0; i < 4; ++i)
#pragma unroll
        for (int j = 0; j < 4; ++j) acc[i][j] += a[i] * b[j];
    }
    __syncthreads();
  }
  const int n = n0 + tx * 4;
  float4 bv = *reinterpret_cast<const float4*>(&bias[n]);
#pragma unroll
  for (int i = 0; i < 4; ++i) {
    const int m = m0 + ty * 4 + i;
    float4 r;
    r.x = acc[i][0] + bv.x; r.y = acc[i][1] + bv.y;
    r.z = acc[i][2] + bv.z; r.w = acc[i][3] + bv.w;
    *reinterpret_cast<float4*>(&C[(size_t)m * NOUT + n]) = r;
  }
}

// ---------------------------------------------------------------------------
// Chunked parallel scan (verified R3/R4): vend (read-only) -> chunks -> fixup.
// ---------------------------------------------------------------------------
__global__ __launch_bounds__(512) void scan_vend(
    const float* __restrict__ C, const float* __restrict__ decay,
    float* __restrict__ vend) {
  const int b = blockIdx.x / NCHUNK;
  const int c = blockIdx.x % NCHUNK;
  const int o = threadIdx.x;
  const float d   = decay[o];
  const float omd = 1.0f - d;
  float v = 0.0f;
  size_t base = ((size_t)b * TT + (size_t)c * CHUNK) * NOUT + o;
#pragma unroll 4
  for (int k = 0; k < CHUNK; ++k) {
    v = d * v + omd * C[base + (size_t)k * NOUT];
  }
  vend[((size_t)b * NCHUNK + c) * NOUT + o] = v;
}

__global__ __launch_bounds__(512) void scan_chunks(
    const float* __restrict__ vend, const float* __restrict__ decay,
    float* __restrict__ vinit) {
  const int b = blockIdx.x;
  const int o = threadIdx.x;
  const float d = decay[o];
  float d2 = d * d, d4 = d2 * d2, d8 = d4 * d4, d16 = d8 * d8;
  const float dL = d16 * d16;   // d^CHUNK
  float V = 0.0f;
  for (int c = 0; c < NCHUNK; ++c) {
    const size_t idx = ((size_t)b * NCHUNK + c) * NOUT + o;
    vinit[idx] = V;
    V = dL * V + vend[idx];
  }
}

__global__ __launch_bounds__(512) void scan_fixup(
    float* __restrict__ C, float* __restrict__ states,
    const float* __restrict__ decay, const float* __restrict__ vinit) {
  const int b = blockIdx.x / NCHUNK;
  const int c = blockIdx.x % NCHUNK;
  const int o = threadIdx.x;
  const float d   = decay[o];
  const float omd = 1.0f - d;
  float v = vinit[((size_t)b * NCHUNK + c) * NOUT + o];  // seed = carry-in
  size_t obase = ((size_t)b * TT + (size_t)c * CHUNK) * NOUT + o;
  size_t sbase = ((size_t)b * (TT + 1) + (size_t)c * CHUNK + 1) * NOUT + o;
#pragma unroll 4
  for (int k = 0; k < CHUNK; ++k) {
    v = d * v + omd * C[obase + (size_t)k * NOUT];
    C[obase + (size_t)k * NOUT]      = v;
    states[sbase + (size_t)k * NOUT] = v;
  }
  if (c == 0) states[((size_t)b * (TT + 1)) * NOUT + o] = 0.0f;
}

__global__ __launch_bounds__(512) void scan_seq(
    float* __restrict__ C, float* __restrict__ states,
    const float* __restrict__ decay) {
  const int b = blockIdx.x;
  const int o = threadIdx.x;
  const float d   = decay[o];
  const float omd = 1.0f - d;
  float v = 0.0f;
  states[((size_t)b * (TT + 1)) * NOUT + o] = 0.0f;
  for (int t = 0; t < TT; ++t) {
    const size_t oi = ((size_t)b * TT + t) * NOUT + o;
    float x = C[oi];
    v = d * v + omd * x;
    C[oi] = v;
    states[((size_t)b * (TT + 1) + t + 1) * NOUT + o] = v;
  }
}

extern "C" void kernel_launch(void* const* d_in, const int* in_sizes, int n_in,
                              void* d_out, int out_size, void* d_ws, size_t ws_size,
                              hipStream_t stream) {
  const float* x     = (const float*)d_in[0];  // [B,T,IN]
  const float* w     = (const float*)d_in[1];  // [OUT,IN]
  const float* bias  = (const float*)d_in[2];  // [OUT]
  const float* decay = (const float*)d_in[3];  // [OUT]

  float* out    = (float*)d_out;                 // [B,T,OUT]
  float* states = out + (size_t)BB * TT * NOUT;  // [1,B,T+1,OUT]

  const size_t szW = (size_t)NOUT * KIN;                      // 0.52M elems
  const size_t scan_elems = (size_t)BB * NCHUNK * NOUT;
  const size_t need = szW * sizeof(_Float16)
                    + 2 * scan_elems * sizeof(float);         // ~3 MB

  if (ws_size >= need) {
    _Float16* Wh = (_Float16*)d_ws;
    float* vend  = (float*)(Wh + szW);
    float* vinit = vend + scan_elems;

    conv_f16_kernel<<<256, 256, 0, stream>>>(w, Wh, (int)(szW / 8));
    gemm_f16<<<dim3((BB * TT) / BM, NOUT / BN), 256, 0, stream>>>(
        x, Wh, bias, out);
    scan_vend  <<<BB * NCHUNK, NOUT, 0, stream>>>(out, decay, vend);
    scan_chunks<<<BB,          NOUT, 0, stream>>>(vend, decay, vinit);
    scan_fixup <<<BB * NCHUNK, NOUT, 0, stream>>>(out, states, decay, vinit);
  } else {
    gemm_f32_64x64<<<dim3(NOUT / 64, (BB * TT) / 64), 256, 0, stream>>>(x, w, bias, out);
    scan_seq<<<BB, NOUT, 0, stream>>>(out, states, decay);
  }
}

// Round 7
// 78.280 us; speedup vs baseline: 1.8226x; 1.8226x over previous
//
#include <hip/hip_runtime.h>
#include <hip/hip_bf16.h>
#include <cstddef>
#include <cstdint>

#define BB    8
#define TT    2048
#define KIN   1024
#define NOUT  512
#define CHUNK 32
#define NCHUNK (TT / CHUNK)   // 64

#define BM 128
#define BN 64
#define BK 32
#define NKSTEP (KIN / BK)     // 32
#define LDSBUF 20480          // A 16KB + B 4KB per buffer

typedef __attribute__((ext_vector_type(4))) float          f32x4;
typedef __attribute__((ext_vector_type(4))) unsigned int   u32x4;
typedef _Float16 f16x8 __attribute__((ext_vector_type(8)));

// ---------------------------------------------------------------------------
// W f32 -> fp16 (RNE).  1 MB output, trivial pass.
// ---------------------------------------------------------------------------
__global__ __launch_bounds__(256) void conv_f16_kernel(
    const float* __restrict__ src, _Float16* __restrict__ dst, int n8) {
  int i = blockIdx.x * blockDim.x + threadIdx.x;
  const int stride = gridDim.x * blockDim.x;
  for (; i < n8; i += stride) {
    float4 x0 = reinterpret_cast<const float4*>(src)[2 * i];
    float4 x1 = reinterpret_cast<const float4*>(src)[2 * i + 1];
    f16x8 h;
    h[0] = (_Float16)x0.x; h[1] = (_Float16)x0.y;
    h[2] = (_Float16)x0.z; h[3] = (_Float16)x0.w;
    h[4] = (_Float16)x1.x; h[5] = (_Float16)x1.y;
    h[6] = (_Float16)x1.z; h[7] = (_Float16)x1.w;
    reinterpret_cast<f16x8*>(dst)[i] = h;
  }
}

#define G2L(gp, sp)                                                        \
  __builtin_amdgcn_global_load_lds(                                       \
      (const __attribute__((address_space(1))) void*)(gp),                \
      (__attribute__((address_space(3))) void*)(sp), 16, 0, 0)

// ---------------------------------------------------------------------------
// fp16 MFMA GEMM, counted-vmcnt double-buffered pipeline (T3/T4 minimum):
//   prologue: stage(0), stage(1)
//   iter t:   s_waitcnt vmcnt(5) [stage(t) landed, stage(t+1) in flight]
//             s_barrier; ds_read + cvt_pkrtz + 8 MFMA; s_barrier;
//             stage(t+2) into buf[t&1]        [5 G2L, fly 2 K-steps]
// A = X f32 staged raw (cvt to fp16 at use); B = fp16 W. Swizzles verified
// R5/R6 (A: slot^=row&7 -> 0 conflicts measured in R6).
// Epilogue fuses scan_vend: C-tile -> LDS -> per-(chunk,feature) local scan.
// grid = (128 m-strips, 8 n-tiles); 128%8==0 -> m-strip's n-blocks share XCD.
// ---------------------------------------------------------------------------
__global__ __launch_bounds__(256, 4) void gemm_f16(
    const float* __restrict__ X, const _Float16* __restrict__ Wh,
    const float* __restrict__ bias, const float* __restrict__ decay,
    float* __restrict__ C, float* __restrict__ vend) {
  __shared__ __align__(16) unsigned char smem[2 * LDSBUF];  // 40KB

  const int tid  = threadIdx.x;
  const int wave = tid >> 6;
  const int lane = tid & 63;
  const int m0 = blockIdx.x * BM;
  const int n0 = blockIdx.y * BN;
  const int wm = (wave >> 1) * 64;   // 2x2 waves: 64x32 output each
  const int wn = (wave & 1) * 32;
  const int frow = lane & 15;

  // --- staging constants (inverse-swizzled global source, linear LDS dest) ---
  const int sgA  = (lane & 7) ^ (lane >> 3);        // A: 16B slot ^= row&7
  const int arow = wave * 8 + (lane >> 3);
  const int sgB  = (lane & 3) ^ ((lane >> 3) & 3);  // B: 16B slot ^= (row>>1)&3
  const int brow = wave * 16 + (lane >> 2);

  const float*    gA = X  + (size_t)(m0 + arow) * KIN + sgA * 4;
  const _Float16* gB = Wh + (size_t)(n0 + brow) * KIN + sgB * 8;
  const int ldsw = wave * 1024;   // bytes: wave's lane-linear slice per issue

  // --- fragment-read constants (swizzled byte offsets, constant per lane) ---
  const int s0  = (lane >> 4) * 2;
  const int oA0 = ((s0)     ^ (lane & 7)) << 4;
  const int oA1 = ((s0 + 1) ^ (lane & 7)) << 4;
  const int oB  = ((lane >> 4) ^ ((lane >> 1) & 3)) << 4;

  f32x4 acc[4][2] = {};

  auto stage = [&](int buf, int k0) {
    unsigned char* bA = smem + buf * LDSBUF;
#pragma unroll
    for (int i = 0; i < 4; ++i)
      G2L(gA + (size_t)i * 32 * KIN + k0, bA + i * 4096 + ldsw);
    G2L(gB + k0, bA + 16384 + ldsw);
  };

  // prologue: two tiles in flight
  stage(0, 0);
  stage(1, BK);

  for (int t = 0; t < NKSTEP; ++t) {
    if (t < NKSTEP - 1) {
      asm volatile("s_waitcnt vmcnt(5)" ::: "memory");  // stage(t) landed
    } else {
      asm volatile("s_waitcnt vmcnt(0)" ::: "memory");
    }
    __builtin_amdgcn_sched_barrier(0);
    __builtin_amdgcn_s_barrier();      // block-wide: buf[t&1] ready

    const unsigned char* cb = smem + (t & 1) * LDSBUF;

    // A fragments: f32 from LDS, packed RTZ convert to fp16
    f16x8 af[4];
#pragma unroll
    for (int mi = 0; mi < 4; ++mi) {
      const unsigned char* ap = cb + (size_t)(wm + mi * 16 + frow) * 128;
      f32x4 q0 = *reinterpret_cast<const f32x4*>(ap + oA0);
      f32x4 q1 = *reinterpret_cast<const f32x4*>(ap + oA1);
      u32x4 hv;
      hv[0] = __builtin_bit_cast(unsigned int, __builtin_amdgcn_cvt_pkrtz(q0[0], q0[1]));
      hv[1] = __builtin_bit_cast(unsigned int, __builtin_amdgcn_cvt_pkrtz(q0[2], q0[3]));
      hv[2] = __builtin_bit_cast(unsigned int, __builtin_amdgcn_cvt_pkrtz(q1[0], q1[1]));
      hv[3] = __builtin_bit_cast(unsigned int, __builtin_amdgcn_cvt_pkrtz(q1[2], q1[3]));
      af[mi] = __builtin_bit_cast(f16x8, hv);
    }

#pragma unroll
    for (int ni = 0; ni < 2; ++ni) {
      const unsigned char* bp = cb + 16384 + (size_t)(wn + ni * 16 + frow) * 64 + oB;
      f16x8 bf = *reinterpret_cast<const f16x8*>(bp);
#pragma unroll
      for (int mi = 0; mi < 4; ++mi)
        acc[mi][ni] = __builtin_amdgcn_mfma_f32_16x16x32_f16(af[mi], bf, acc[mi][ni], 0, 0, 0);
    }

    __builtin_amdgcn_s_barrier();      // block-wide: buf[t&1] reads done
    __builtin_amdgcn_sched_barrier(0);
    if (t + 2 < NKSTEP) stage(t & 1, (t + 2) * BK);
  }

  // --- epilogue: bias add, store C, stash tile in LDS for fused vend scan ---
  float* cl = reinterpret_cast<float*>(smem);   // 128x64 f32 = 32KB
  const int colb = n0 + wn + (lane & 15);
  const int rowb = m0 + wm + ((lane >> 4) << 2);
  const int lcol = wn + (lane & 15);
  const int lrow = wm + ((lane >> 4) << 2);
#pragma unroll
  for (int ni = 0; ni < 2; ++ni) {
    const float bv = bias[colb + ni * 16];
#pragma unroll
    for (int mi = 0; mi < 4; ++mi) {
#pragma unroll
      for (int r = 0; r < 4; ++r) {
        const float val = acc[mi][ni][r] + bv;
        C[(size_t)(rowb + mi * 16 + r) * NOUT + colb + ni * 16] = val;
        cl[(lrow + mi * 16 + r) * 64 + lcol + ni * 16] = val;
      }
    }
  }
  __syncthreads();

  // fused scan_vend: 4 chunks x 64 features; thread = (chunk cc, feature f)
  {
    const int cc = tid >> 6;          // 0..3
    const int f  = tid & 63;
    const int b  = m0 >> 11;          // m0 / TT
    const int c0 = (m0 & (TT - 1)) >> 5;
    const float d   = decay[n0 + f];
    const float omd = 1.0f - d;
    float v = 0.0f;
    const float* col = cl + cc * 32 * 64 + f;
#pragma unroll 8
    for (int k = 0; k < 32; ++k) v = d * v + omd * col[k * 64];
    vend[((size_t)b * NCHUNK + c0 + cc) * NOUT + n0 + f] = v;
  }
}

// ---------------------------------------------------------------------------
// Fallback f32 GEMM (verified R1) — only if workspace is too small.
// ---------------------------------------------------------------------------
__global__ __launch_bounds__(256) void gemm_f32_64x64(
    const float* __restrict__ X, const float* __restrict__ W,
    const float* __restrict__ bias, float* __restrict__ C) {
  __shared__ float As[16][65];
  __shared__ float Bs[16][65];
  const int m0  = blockIdx.y * 64;
  const int n0  = blockIdx.x * 64;
  const int tid = threadIdx.x;
  const int tx  = tid & 15;
  const int ty  = tid >> 4;
  const int lr  = tid >> 2;
  const int lk  = (tid & 3) << 2;
  float acc[4][4] = {};
  const float* xa = X + (size_t)(m0 + lr) * KIN + lk;
  const float* wb = W + (size_t)(n0 + lr) * KIN + lk;
  for (int k0 = 0; k0 < KIN; k0 += 16) {
    float4 av = *reinterpret_cast<const float4*>(xa + k0);
    float4 bv = *reinterpret_cast<const float4*>(wb + k0);
    As[lk + 0][lr] = av.x; As[lk + 1][lr] = av.y;
    As[lk + 2][lr] = av.z; As[lk + 3][lr] = av.w;
    Bs[lk + 0][lr] = bv.x; Bs[lk + 1][lr] = bv.y;
    Bs[lk + 2][lr] = bv.z; Bs[lk + 3][lr] = bv.w;
    __syncthreads();
#pragma unroll
    for (int k = 0; k < 16; ++k) {
      float a[4], b[4];
#pragma unroll
      for (int i = 0; i < 4; ++i) a[i] = As[k][ty * 4 + i];
#pragma unroll
      for (int j = 0; j < 4; ++j) b[j] = Bs[k][tx * 4 + j];
#pragma unroll
      for (int i = 0; i < 4; ++i)
#pragma unroll
        for (int j = 0; j < 4; ++j) acc[i][j] += a[i] * b[j];
    }
    __syncthreads();
  }
  const int n = n0 + tx * 4;
  float4 bv = *reinterpret_cast<const float4*>(&bias[n]);
#pragma unroll
  for (int i = 0; i < 4; ++i) {
    const int m = m0 + ty * 4 + i;
    float4 r;
    r.x = acc[i][0] + bv.x; r.y = acc[i][1] + bv.y;
    r.z = acc[i][2] + bv.z; r.w = acc[i][3] + bv.w;
    *reinterpret_cast<float4*>(&C[(size_t)m * NOUT + n]) = r;
  }
}

// ---------------------------------------------------------------------------
// Chunk-carry compose + fixup (verified R3-R6).  vend now from GEMM epilogue.
// ---------------------------------------------------------------------------
__global__ __launch_bounds__(512) void scan_vend(
    const float* __restrict__ C, const float* __restrict__ decay,
    float* __restrict__ vend) {
  const int b = blockIdx.x / NCHUNK;
  const int c = blockIdx.x % NCHUNK;
  const int o = threadIdx.x;
  const float d   = decay[o];
  const float omd = 1.0f - d;
  float v = 0.0f;
  size_t base = ((size_t)b * TT + (size_t)c * CHUNK) * NOUT + o;
#pragma unroll 4
  for (int k = 0; k < CHUNK; ++k) {
    v = d * v + omd * C[base + (size_t)k * NOUT];
  }
  vend[((size_t)b * NCHUNK + c) * NOUT + o] = v;
}

__global__ __launch_bounds__(512) void scan_chunks(
    const float* __restrict__ vend, const float* __restrict__ decay,
    float* __restrict__ vinit) {
  const int b = blockIdx.x;
  const int o = threadIdx.x;
  const float d = decay[o];
  float d2 = d * d, d4 = d2 * d2, d8 = d4 * d4, d16 = d8 * d8;
  const float dL = d16 * d16;   // d^CHUNK
  float V = 0.0f;
  for (int c = 0; c < NCHUNK; ++c) {
    const size_t idx = ((size_t)b * NCHUNK + c) * NOUT + o;
    vinit[idx] = V;
    V = dL * V + vend[idx];
  }
}

__global__ __launch_bounds__(512) void scan_fixup(
    float* __restrict__ C, float* __restrict__ states,
    const float* __restrict__ decay, const float* __restrict__ vinit) {
  const int b = blockIdx.x / NCHUNK;
  const int c = blockIdx.x % NCHUNK;
  const int o = threadIdx.x;
  const float d   = decay[o];
  const float omd = 1.0f - d;
  float v = vinit[((size_t)b * NCHUNK + c) * NOUT + o];  // seed = carry-in
  size_t obase = ((size_t)b * TT + (size_t)c * CHUNK) * NOUT + o;
  size_t sbase = ((size_t)b * (TT + 1) + (size_t)c * CHUNK + 1) * NOUT + o;
#pragma unroll 4
  for (int k = 0; k < CHUNK; ++k) {
    v = d * v + omd * C[obase + (size_t)k * NOUT];
    C[obase + (size_t)k * NOUT]      = v;
    states[sbase + (size_t)k * NOUT] = v;
  }
  if (c == 0) states[((size_t)b * (TT + 1)) * NOUT + o] = 0.0f;
}

__global__ __launch_bounds__(512) void scan_seq(
    float* __restrict__ C, float* __restrict__ states,
    const float* __restrict__ decay) {
  const int b = blockIdx.x;
  const int o = threadIdx.x;
  const float d   = decay[o];
  const float omd = 1.0f - d;
  float v = 0.0f;
  states[((size_t)b * (TT + 1)) * NOUT + o] = 0.0f;
  for (int t = 0; t < TT; ++t) {
    const size_t oi = ((size_t)b * TT + t) * NOUT + o;
    float x = C[oi];
    v = d * v + omd * x;
    C[oi] = v;
    states[((size_t)b * (TT + 1) + t + 1) * NOUT + o] = v;
  }
}

extern "C" void kernel_launch(void* const* d_in, const int* in_sizes, int n_in,
                              void* d_out, int out_size, void* d_ws, size_t ws_size,
                              hipStream_t stream) {
  const float* x     = (const float*)d_in[0];  // [B,T,IN]
  const float* w     = (const float*)d_in[1];  // [OUT,IN]
  const float* bias  = (const float*)d_in[2];  // [OUT]
  const float* decay = (const float*)d_in[3];  // [OUT]

  float* out    = (float*)d_out;                 // [B,T,OUT]
  float* states = out + (size_t)BB * TT * NOUT;  // [1,B,T+1,OUT]

  const size_t szW = (size_t)NOUT * KIN;                      // 0.52M elems
  const size_t scan_elems = (size_t)BB * NCHUNK * NOUT;
  const size_t need = szW * sizeof(_Float16)
                    + 2 * scan_elems * sizeof(float);         // ~3 MB

  if (ws_size >= need) {
    _Float16* Wh = (_Float16*)d_ws;
    float* vend  = (float*)(Wh + szW);
    float* vinit = vend + scan_elems;

    conv_f16_kernel<<<256, 256, 0, stream>>>(w, Wh, (int)(szW / 8));
    gemm_f16<<<dim3((BB * TT) / BM, NOUT / BN), 256, 0, stream>>>(
        x, Wh, bias, decay, out, vend);
    scan_chunks<<<BB, NOUT, 0, stream>>>(vend, decay, vinit);
    scan_fixup <<<BB * NCHUNK, NOUT, 0, stream>>>(out, states, decay, vinit);
  } else {
    gemm_f32_64x64<<<dim3(NOUT / 64, (BB * TT) / 64), 256, 0, stream>>>(x, w, bias, out);
    scan_seq<<<BB, NOUT, 0, stream>>>(out, states, decay);
  }
}

// Round 8
// 76.683 us; speedup vs baseline: 1.8606x; 1.0208x over previous
//
#include <hip/hip_runtime.h>
#include <hip/hip_bf16.h>
#include <cstddef>
#include <cstdint>

#define BB    8
#define TT    2048
#define KIN   1024
#define NOUT  512
#define CHUNK 32
#define NCHUNK (TT / CHUNK)   // 64

#define BM 128
#define BN 64
#define BK 32
#define NKSTEP (KIN / BK)     // 32

typedef __attribute__((ext_vector_type(4))) float          f32x4;
typedef __attribute__((ext_vector_type(4))) unsigned int   u32x4;
typedef _Float16 f16x8 __attribute__((ext_vector_type(8)));

// ---------------------------------------------------------------------------
// W f32 -> fp16 (RNE).  1 MB output, trivial pass.
// ---------------------------------------------------------------------------
__global__ __launch_bounds__(256) void conv_f16_kernel(
    const float* __restrict__ src, _Float16* __restrict__ dst, int n8) {
  int i = blockIdx.x * blockDim.x + threadIdx.x;
  const int stride = gridDim.x * blockDim.x;
  for (; i < n8; i += stride) {
    float4 x0 = reinterpret_cast<const float4*>(src)[2 * i];
    float4 x1 = reinterpret_cast<const float4*>(src)[2 * i + 1];
    f16x8 h;
    h[0] = (_Float16)x0.x; h[1] = (_Float16)x0.y;
    h[2] = (_Float16)x0.z; h[3] = (_Float16)x0.w;
    h[4] = (_Float16)x1.x; h[5] = (_Float16)x1.y;
    h[6] = (_Float16)x1.z; h[7] = (_Float16)x1.w;
    reinterpret_cast<f16x8*>(dst)[i] = h;
  }
}

#define G2L(gp, sp)                                                        \
  __builtin_amdgcn_global_load_lds(                                       \
      (const __attribute__((address_space(1))) void*)(gp),                \
      (__attribute__((address_space(3))) void*)(sp), 16, 0, 0)

// ---------------------------------------------------------------------------
// fp16 MFMA GEMM, LDS-traffic-minimized:
//  - A (X, f32): global->VGPR (128B-per-row coalesced map), cvt_pkrtz -> f16,
//    swizzled ds_write_b64 into a SINGLE 8KB f16 buffer.
//  - B (W, f16): G2L into double-buffered 2x4KB.
//  - Loop: sync1 (drain loads) | ds_write A(t) | sync2 (lgkm only) |
//          prefetch A(t+1)+B(t+1) | compute(t).  Plain __syncthreads only.
//  - Epilogue fuses vend scan via in-register Horner + shfl_xor reduce.
// LDS swizzle: LDS[r][s^((r>>1)&3)] = G[r][s] on both A and B (<=2-way banks).
// grid = (128 m-strips, 8 n-tiles); 128%8==0 -> m-strip's n-blocks share XCD.
// ---------------------------------------------------------------------------
__global__ __launch_bounds__(256, 4) void gemm_f16(
    const float* __restrict__ X, const _Float16* __restrict__ Wh,
    const float* __restrict__ bias, const float* __restrict__ decay,
    float* __restrict__ C, float* __restrict__ vend) {
  // A f16 8KB | B f16 dbuf 2x4KB = 16KB
  __shared__ __align__(16) unsigned char smem[8192 + 2 * 4096];

  const int tid  = threadIdx.x;
  const int wave = tid >> 6;
  const int lane = tid & 63;
  const int m0 = blockIdx.x * BM;
  const int n0 = blockIdx.y * BN;
  const int wm = (wave >> 1) * 64;   // 2x2 waves: 64x32 output each
  const int wn = (wave & 1) * 32;
  const int frow = lane & 15;
  const int g    = lane >> 4;        // k-slice / quad-group

  // --- A staging: lane covers 16B of X row (8 lanes = full 128B k-window) ---
  const int ar = wave * 8 + (lane >> 3);      // base row 0..31 (4 rows of 32)
  const int as = lane & 7;                    // f32 16B slot in 128B window
  const float* gA = X + (size_t)(m0 + ar) * KIN + as * 4;
  // f16 row = 64B = 4 slots; this lane's 8B lands at slot (as>>1), half (as&1)
  const int awb = ((as >> 1) ^ ((ar >> 1) & 3)) * 16 + (as & 1) * 8;

  // --- B staging via G2L (verified R5): LDS[r][s] = G[r][s^((r>>1)&3)] ---
  const int brow = wave * 16 + (lane >> 2);
  const int sgB  = (lane & 3) ^ ((lane >> 3) & 3);
  const _Float16* gB = Wh + (size_t)(n0 + brow) * KIN + sgB * 8;

  // --- fragment-read swizzled offsets ---
  const int swzr = (g ^ ((frow >> 1) & 3)) << 4;   // + row*64

  f32x4 acc[4][2] = {};
  f32x4 ra0, ra1, ra2, ra3;

  // prologue: A(0) loads + B(0) G2L
  ra0 = *reinterpret_cast<const f32x4*>(gA);
  ra1 = *reinterpret_cast<const f32x4*>(gA + (size_t)32 * KIN);
  ra2 = *reinterpret_cast<const f32x4*>(gA + (size_t)64 * KIN);
  ra3 = *reinterpret_cast<const f32x4*>(gA + (size_t)96 * KIN);
  G2L(gB, smem + 8192 + wave * 1024);

  for (int t = 0; t < NKSTEP; ++t) {
    __syncthreads();   // compute(t-1) done; A(t) regs + B(t) G2L drained

    // ds_write A(t): 4 rows x 8B (pkrtz pairs), swizzled
    {
      uint2 w;
      w.x = __builtin_bit_cast(unsigned int, __builtin_amdgcn_cvt_pkrtz(ra0[0], ra0[1]));
      w.y = __builtin_bit_cast(unsigned int, __builtin_amdgcn_cvt_pkrtz(ra0[2], ra0[3]));
      *reinterpret_cast<uint2*>(smem + (ar +  0) * 64 + awb) = w;
      w.x = __builtin_bit_cast(unsigned int, __builtin_amdgcn_cvt_pkrtz(ra1[0], ra1[1]));
      w.y = __builtin_bit_cast(unsigned int, __builtin_amdgcn_cvt_pkrtz(ra1[2], ra1[3]));
      *reinterpret_cast<uint2*>(smem + (ar + 32) * 64 + awb) = w;
      w.x = __builtin_bit_cast(unsigned int, __builtin_amdgcn_cvt_pkrtz(ra2[0], ra2[1]));
      w.y = __builtin_bit_cast(unsigned int, __builtin_amdgcn_cvt_pkrtz(ra2[2], ra2[3]));
      *reinterpret_cast<uint2*>(smem + (ar + 64) * 64 + awb) = w;
      w.x = __builtin_bit_cast(unsigned int, __builtin_amdgcn_cvt_pkrtz(ra3[0], ra3[1]));
      w.y = __builtin_bit_cast(unsigned int, __builtin_amdgcn_cvt_pkrtz(ra3[2], ra3[3]));
      *reinterpret_cast<uint2*>(smem + (ar + 96) * 64 + awb) = w;
    }
    __syncthreads();   // ds_writes visible (lgkm-only drain: cheap)

    // prefetch t+1: A->VGPR, B->other LDS buffer (fly under compute)
    if (t + 1 < NKSTEP) {
      const int k0 = (t + 1) * BK;
      ra0 = *reinterpret_cast<const f32x4*>(gA + k0);
      ra1 = *reinterpret_cast<const f32x4*>(gA + (size_t)32 * KIN + k0);
      ra2 = *reinterpret_cast<const f32x4*>(gA + (size_t)64 * KIN + k0);
      ra3 = *reinterpret_cast<const f32x4*>(gA + (size_t)96 * KIN + k0);
      G2L(gB + k0, smem + 8192 + ((t + 1) & 1) * 4096 + wave * 1024);
    }

    // compute(t)
    const unsigned char* bB = smem + 8192 + (t & 1) * 4096;
    f16x8 af[4];
#pragma unroll
    for (int mi = 0; mi < 4; ++mi)
      af[mi] = *reinterpret_cast<const f16x8*>(smem + (wm + mi * 16 + frow) * 64 + swzr);
#pragma unroll
    for (int ni = 0; ni < 2; ++ni) {
      f16x8 bf = *reinterpret_cast<const f16x8*>(bB + (wn + ni * 16 + frow) * 64 + swzr);
#pragma unroll
      for (int mi = 0; mi < 4; ++mi)
        acc[mi][ni] = __builtin_amdgcn_mfma_f32_16x16x32_f16(af[mi], bf, acc[mi][ni], 0, 0, 0);
    }
  }

  // --- epilogue: bias + C store + fused vend (in-register, shfl reduce) ---
  const int colb = n0 + wn + frow;            // ni=0 column
  const int rowb = m0 + wm + (g << 2);
  const float bv0 = bias[colb];
  const float bv1 = bias[colb + 16];
#pragma unroll
  for (int mi = 0; mi < 4; ++mi) {
#pragma unroll
    for (int r = 0; r < 4; ++r) {
      C[(size_t)(rowb + mi * 16 + r) * NOUT + colb]      = acc[mi][0][r] + bv0;
      C[(size_t)(rowb + mi * 16 + r) * NOUT + colb + 16] = acc[mi][1][r] + bv1;
    }
  }

  // vend: chunk-lo = rows wm..wm+31 (mi 0,1), chunk-hi = wm+32.. (mi 2,3).
  // lane's 4 rows are consecutive (4g..4g+3): Horner -> weight d^(4(3-g)) ->
  // shfl_xor(16,32) sums the 4 quad-groups.  vend_chunk = S(mi_a)*d^16 + S(mi_b).
  {
    const float d0 = decay[colb];
    const float d1 = decay[colb + 16];
    float rr[2][2];  // [chunk half][ni]
#pragma unroll
    for (int ni = 0; ni < 2; ++ni) {
      const float d = ni ? d1 : d0;
      const float bv = ni ? bv1 : bv0;
      const float omd = 1.0f - d;
      const float dd = d * d, d4 = dd * dd, d8 = d4 * d4;
      const float d16 = d8 * d8, d12 = d8 * d4;
      const float dpg = (g == 0) ? d12 : (g == 1) ? d8 : (g == 2) ? d4 : 1.0f;
      float s[4];
#pragma unroll
      for (int mi = 0; mi < 4; ++mi) {
        float v = acc[mi][ni][0] + bv;
        v = v * d + (acc[mi][ni][1] + bv);
        v = v * d + (acc[mi][ni][2] + bv);
        v = v * d + (acc[mi][ni][3] + bv);
        s[mi] = omd * v;
      }
      float ulo = dpg * (s[0] * d16 + s[1]);
      float uhi = dpg * (s[2] * d16 + s[3]);
      ulo += __shfl_xor(ulo, 16); ulo += __shfl_xor(ulo, 32);
      uhi += __shfl_xor(uhi, 16); uhi += __shfl_xor(uhi, 32);
      rr[0][ni] = ulo; rr[1][ni] = uhi;
    }
    const int b     = m0 >> 11;                       // m0 / TT
    const int clo   = ((m0 & (TT - 1)) >> 5) + (wm >> 5);
    const float val = rr[g >> 1][g & 1];
    const int chunk = clo + (g >> 1);
    const int col   = n0 + wn + frow + (g & 1) * 16;
    vend[((size_t)b * NCHUNK + chunk) * NOUT + col] = val;
  }
}

// ---------------------------------------------------------------------------
// Fallback f32 GEMM (verified R1) — only if workspace is too small.
// ---------------------------------------------------------------------------
__global__ __launch_bounds__(256) void gemm_f32_64x64(
    const float* __restrict__ X, const float* __restrict__ W,
    const float* __restrict__ bias, float* __restrict__ C) {
  __shared__ float As[16][65];
  __shared__ float Bs[16][65];
  const int m0  = blockIdx.y * 64;
  const int n0  = blockIdx.x * 64;
  const int tid = threadIdx.x;
  const int tx  = tid & 15;
  const int ty  = tid >> 4;
  const int lr  = tid >> 2;
  const int lk  = (tid & 3) << 2;
  float acc[4][4] = {};
  const float* xa = X + (size_t)(m0 + lr) * KIN + lk;
  const float* wb = W + (size_t)(n0 + lr) * KIN + lk;
  for (int k0 = 0; k0 < KIN; k0 += 16) {
    float4 av = *reinterpret_cast<const float4*>(xa + k0);
    float4 bv = *reinterpret_cast<const float4*>(wb + k0);
    As[lk + 0][lr] = av.x; As[lk + 1][lr] = av.y;
    As[lk + 2][lr] = av.z; As[lk + 3][lr] = av.w;
    Bs[lk + 0][lr] = bv.x; Bs[lk + 1][lr] = bv.y;
    Bs[lk + 2][lr] = bv.z; Bs[lk + 3][lr] = bv.w;
    __syncthreads();
#pragma unroll
    for (int k = 0; k < 16; ++k) {
      float a[4], b[4];
#pragma unroll
      for (int i = 0; i < 4; ++i) a[i] = As[k][ty * 4 + i];
#pragma unroll
      for (int j = 0; j < 4; ++j) b[j] = Bs[k][tx * 4 + j];
#pragma unroll
      for (int i = 0; i < 4; ++i)
#pragma unroll
        for (int j = 0; j < 4; ++j) acc[i][j] += a[i] * b[j];
    }
    __syncthreads();
  }
  const int n = n0 + tx * 4;
  float4 bv = *reinterpret_cast<const float4*>(&bias[n]);
#pragma unroll
  for (int i = 0; i < 4; ++i) {
    const int m = m0 + ty * 4 + i;
    float4 r;
    r.x = acc[i][0] + bv.x; r.y = acc[i][1] + bv.y;
    r.z = acc[i][2] + bv.z; r.w = acc[i][3] + bv.w;
    *reinterpret_cast<float4*>(&C[(size_t)m * NOUT + n]) = r;
  }
}

// ---------------------------------------------------------------------------
// Chunk-carry compose + fixup (verified R3-R7). vend comes from GEMM epilogue.
// ---------------------------------------------------------------------------
__global__ __launch_bounds__(512) void scan_chunks(
    const float* __restrict__ vend, const float* __restrict__ decay,
    float* __restrict__ vinit) {
  const int b = blockIdx.x;
  const int o = threadIdx.x;
  const float d = decay[o];
  float d2 = d * d, d4 = d2 * d2, d8 = d4 * d4, d16 = d8 * d8;
  const float dL = d16 * d16;   // d^CHUNK
  float V = 0.0f;
  for (int c = 0; c < NCHUNK; ++c) {
    const size_t idx = ((size_t)b * NCHUNK + c) * NOUT + o;
    vinit[idx] = V;
    V = dL * V + vend[idx];
  }
}

__global__ __launch_bounds__(512) void scan_fixup(
    float* __restrict__ C, float* __restrict__ states,
    const float* __restrict__ decay, const float* __restrict__ vinit) {
  const int b = blockIdx.x / NCHUNK;
  const int c = blockIdx.x % NCHUNK;
  const int o = threadIdx.x;
  const float d   = decay[o];
  const float omd = 1.0f - d;
  float v = vinit[((size_t)b * NCHUNK + c) * NOUT + o];  // seed = carry-in
  size_t obase = ((size_t)b * TT + (size_t)c * CHUNK) * NOUT + o;
  size_t sbase = ((size_t)b * (TT + 1) + (size_t)c * CHUNK + 1) * NOUT + o;
#pragma unroll 4
  for (int k = 0; k < CHUNK; ++k) {
    v = d * v + omd * C[obase + (size_t)k * NOUT];
    C[obase + (size_t)k * NOUT]      = v;
    states[sbase + (size_t)k * NOUT] = v;
  }
  if (c == 0) states[((size_t)b * (TT + 1)) * NOUT + o] = 0.0f;
}

__global__ __launch_bounds__(512) void scan_seq(
    float* __restrict__ C, float* __restrict__ states,
    const float* __restrict__ decay) {
  const int b = blockIdx.x;
  const int o = threadIdx.x;
  const float d   = decay[o];
  const float omd = 1.0f - d;
  float v = 0.0f;
  states[((size_t)b * (TT + 1)) * NOUT + o] = 0.0f;
  for (int t = 0; t < TT; ++t) {
    const size_t oi = ((size_t)b * TT + t) * NOUT + o;
    float x = C[oi];
    v = d * v + omd * x;
    C[oi] = v;
    states[((size_t)b * (TT + 1) + t + 1) * NOUT + o] = v;
  }
}

extern "C" void kernel_launch(void* const* d_in, const int* in_sizes, int n_in,
                              void* d_out, int out_size, void* d_ws, size_t ws_size,
                              hipStream_t stream) {
  const float* x     = (const float*)d_in[0];  // [B,T,IN]
  const float* w     = (const float*)d_in[1];  // [OUT,IN]
  const float* bias  = (const float*)d_in[2];  // [OUT]
  const float* decay = (const float*)d_in[3];  // [OUT]

  float* out    = (float*)d_out;                 // [B,T,OUT]
  float* states = out + (size_t)BB * TT * NOUT;  // [1,B,T+1,OUT]

  const size_t szW = (size_t)NOUT * KIN;                      // 0.52M elems
  const size_t scan_elems = (size_t)BB * NCHUNK * NOUT;
  const size_t need = szW * sizeof(_Float16)
                    + 2 * scan_elems * sizeof(float);         // ~3 MB

  if (ws_size >= need) {
    _Float16* Wh = (_Float16*)d_ws;
    float* vend  = (float*)(Wh + szW);
    float* vinit = vend + scan_elems;

    conv_f16_kernel<<<256, 256, 0, stream>>>(w, Wh, (int)(szW / 8));
    gemm_f16<<<dim3((BB * TT) / BM, NOUT / BN), 256, 0, stream>>>(
        x, Wh, bias, decay, out, vend);
    scan_chunks<<<BB, NOUT, 0, stream>>>(vend, decay, vinit);
    scan_fixup <<<BB * NCHUNK, NOUT, 0, stream>>>(out, states, decay, vinit);
  } else {
    gemm_f32_64x64<<<dim3(NOUT / 64, (BB * TT) / 64), 256, 0, stream>>>(x, w, bias, out);
    scan_seq<<<BB, NOUT, 0, stream>>>(out, states, decay);
  }
}

// Round 9
// 73.282 us; speedup vs baseline: 1.9469x; 1.0464x over previous
//
#include <hip/hip_runtime.h>
#include <hip/hip_bf16.h>
#include <cstddef>
#include <cstdint>

#define BB    8
#define TT    2048
#define KIN   1024
#define NOUT  512
#define CHUNK 32
#define NCHUNK (TT / CHUNK)   // 64

#define BM 128
#define BN 64
#define BK 32
#define NKSTEP (KIN / BK)     // 32

#define ABUF 8192             // A f16 128x32 per buffer
#define BBUF 4096             // B f16 64x32 per buffer

typedef __attribute__((ext_vector_type(4))) float          f32x4;
typedef __attribute__((ext_vector_type(4))) unsigned int   u32x4;
typedef _Float16 f16x8 __attribute__((ext_vector_type(8)));

// ---------------------------------------------------------------------------
// W f32 -> fp16 (RNE).  1 MB output, trivial pass.
// ---------------------------------------------------------------------------
__global__ __launch_bounds__(256) void conv_f16_kernel(
    const float* __restrict__ src, _Float16* __restrict__ dst, int n8) {
  int i = blockIdx.x * blockDim.x + threadIdx.x;
  const int stride = gridDim.x * blockDim.x;
  for (; i < n8; i += stride) {
    float4 x0 = reinterpret_cast<const float4*>(src)[2 * i];
    float4 x1 = reinterpret_cast<const float4*>(src)[2 * i + 1];
    f16x8 h;
    h[0] = (_Float16)x0.x; h[1] = (_Float16)x0.y;
    h[2] = (_Float16)x0.z; h[3] = (_Float16)x0.w;
    h[4] = (_Float16)x1.x; h[5] = (_Float16)x1.y;
    h[6] = (_Float16)x1.z; h[7] = (_Float16)x1.w;
    reinterpret_cast<f16x8*>(dst)[i] = h;
  }
}

// ---------------------------------------------------------------------------
// fp16 MFMA GEMM — 2-deep reg-staged pipeline, ONE bare barrier per K-step.
//  - NO global_load_lds anywhere: A and B both global->VGPR, so no vmcnt(0)
//    drain at barriers; loads issued 2 K-steps ahead stay in flight and the
//    compiler inserts precise vmcnt(N) only at the ds_write dependence.
//  - A: f32x4 x4 rows -> cvt_pkrtz -> swizzled ds_write (layout == R8, 0-conf).
//  - B: 16B/thread -> swizzled ds_write (layout == R8's G2L result, 0-conf).
//  - LDS: A dbuf 2x8KB + B dbuf 2x4KB = 24KB.
//  - Loop 2x unrolled: two static reg sets (no runtime indexing -> no scratch).
//  - Epilogue fuses vend chunk-scan (in-register Horner + shfl_xor; verified R8).
// grid = (128 m-strips, 8 n-tiles); same-m blocks differ by 128 in linear id
// (128%8==0) -> share an XCD -> X rows hit in L2 (verified R3+: FETCH ~45MB).
// ---------------------------------------------------------------------------
__global__ __launch_bounds__(256, 4) void gemm_f16(
    const float* __restrict__ X, const _Float16* __restrict__ Wh,
    const float* __restrict__ bias, const float* __restrict__ decay,
    float* __restrict__ C, float* __restrict__ vend) {
  __shared__ __align__(16) unsigned char smem[2 * ABUF + 2 * BBUF];

  const int tid  = threadIdx.x;
  const int wave = tid >> 6;
  const int lane = tid & 63;
  const int m0 = blockIdx.x * BM;
  const int n0 = blockIdx.y * BN;
  const int wm = (wave >> 1) * 64;   // 2x2 waves: 64x32 output each
  const int wn = (wave & 1) * 32;
  const int frow = lane & 15;
  const int g    = lane >> 4;        // k-slice / quad-group

  unsigned char* bufA0 = smem;
  unsigned char* bufA1 = smem + ABUF;
  unsigned char* bufB0 = smem + 2 * ABUF;
  unsigned char* bufB1 = smem + 2 * ABUF + BBUF;

  // --- A staging map (verified R8): row ar(+32k), slot as; swizzled write ---
  const int ar = wave * 8 + (lane >> 3);      // 0..31
  const int as = lane & 7;                    // f32 16B slot in 128B window
  const float* gA = X + (size_t)(m0 + ar) * KIN + as * 4;
  const int awb = ((as >> 1) ^ ((ar >> 1) & 3)) * 16 + (as & 1) * 8;

  // --- B staging map (reg-staged; same final layout as R8's G2L+preswizzle:
  //     LDS[r][s] = G[r][s ^ ((r>>1)&3)]) ---
  const int br = wave * 16 + (lane >> 2);     // 0..63
  const int sb = lane & 3;                    // 16B slot in LDS row
  const _Float16* gB = Wh + (size_t)(n0 + br) * KIN + (sb ^ ((br >> 1) & 3)) * 8;
  const int bwb = br * 64 + sb * 16;

  // --- fragment-read swizzled offsets (verified R8: ~0 conflicts) ---
  const int swzr = (g ^ ((frow >> 1) & 3)) << 4;   // + row*64

  f32x4 acc[4][2] = {};

  // two static register sets (A: 4 x f32x4, B: 1 x f16x8-worth = 16B)
  f32x4 rA0_a, rA1_a, rA2_a, rA3_a;  u32x4 rB_a;
  f32x4 rA0_b, rA1_b, rA2_b, rA3_b;  u32x4 rB_b;

#define LOADSET(S, k0)                                                        \
  do {                                                                        \
    rA0_##S = *reinterpret_cast<const f32x4*>(gA + (k0));                     \
    rA1_##S = *reinterpret_cast<const f32x4*>(gA + (size_t)32 * KIN + (k0));  \
    rA2_##S = *reinterpret_cast<const f32x4*>(gA + (size_t)64 * KIN + (k0));  \
    rA3_##S = *reinterpret_cast<const f32x4*>(gA + (size_t)96 * KIN + (k0));  \
    rB_##S  = *reinterpret_cast<const u32x4*>(gB + (k0));                     \
  } while (0)

#define STORESET(S, dA, dB)                                                   \
  do {                                                                        \
    uint2 w;                                                                  \
    w.x = __builtin_bit_cast(unsigned int, __builtin_amdgcn_cvt_pkrtz(rA0_##S[0], rA0_##S[1])); \
    w.y = __builtin_bit_cast(unsigned int, __builtin_amdgcn_cvt_pkrtz(rA0_##S[2], rA0_##S[3])); \
    *reinterpret_cast<uint2*>((dA) + (ar +  0) * 64 + awb) = w;               \
    w.x = __builtin_bit_cast(unsigned int, __builtin_amdgcn_cvt_pkrtz(rA1_##S[0], rA1_##S[1])); \
    w.y = __builtin_bit_cast(unsigned int, __builtin_amdgcn_cvt_pkrtz(rA1_##S[2], rA1_##S[3])); \
    *reinterpret_cast<uint2*>((dA) + (ar + 32) * 64 + awb) = w;               \
    w.x = __builtin_bit_cast(unsigned int, __builtin_amdgcn_cvt_pkrtz(rA2_##S[0], rA2_##S[1])); \
    w.y = __builtin_bit_cast(unsigned int, __builtin_amdgcn_cvt_pkrtz(rA2_##S[2], rA2_##S[3])); \
    *reinterpret_cast<uint2*>((dA) + (ar + 64) * 64 + awb) = w;               \
    w.x = __builtin_bit_cast(unsigned int, __builtin_amdgcn_cvt_pkrtz(rA3_##S[0], rA3_##S[1])); \
    w.y = __builtin_bit_cast(unsigned int, __builtin_amdgcn_cvt_pkrtz(rA3_##S[2], rA3_##S[3])); \
    *reinterpret_cast<uint2*>((dA) + (ar + 96) * 64 + awb) = w;               \
    *reinterpret_cast<u32x4*>((dB) + bwb) = rB_##S;                           \
  } while (0)

#define COMPUTE(cA, cB)                                                       \
  do {                                                                        \
    f16x8 af[4];                                                              \
    _Pragma("unroll")                                                         \
    for (int mi = 0; mi < 4; ++mi)                                            \
      af[mi] = *reinterpret_cast<const f16x8*>((cA) + (wm + mi * 16 + frow) * 64 + swzr); \
    _Pragma("unroll")                                                         \
    for (int ni = 0; ni < 2; ++ni) {                                          \
      f16x8 bf = *reinterpret_cast<const f16x8*>((cB) + (wn + ni * 16 + frow) * 64 + swzr); \
      _Pragma("unroll")                                                       \
      for (int mi = 0; mi < 4; ++mi)                                          \
        acc[mi][ni] = __builtin_amdgcn_mfma_f32_16x16x32_f16(af[mi], bf, acc[mi][ni], 0, 0, 0); \
    }                                                                         \
  } while (0)

#define BARRIER()                                                             \
  do {                                                                        \
    asm volatile("s_waitcnt lgkmcnt(0)" ::: "memory");                        \
    __builtin_amdgcn_s_barrier();                                             \
  } while (0)

  // prologue: tiles 0,1 -> regs; tile 0 -> buf0; reload set a with tile 2
  LOADSET(a, 0);
  LOADSET(b, BK);
  STORESET(a, bufA0, bufB0);
  LOADSET(a, 2 * BK);
  BARRIER();

  for (int tt = 0; tt < NKSTEP; tt += 2) {
    // EVEN step t=tt: compute buf0 (tile tt); stage tile tt+1 from set b -> buf1;
    //                 re-issue set b = tile tt+3
    STORESET(b, bufA1, bufB1);
    if (tt + 3 < NKSTEP) LOADSET(b, (tt + 3) * BK);
    COMPUTE(bufA0, bufB0);
    BARRIER();

    // ODD step t=tt+1: compute buf1 (tile tt+1); stage tile tt+2 from set a -> buf0;
    //                  re-issue set a = tile tt+4
    if (tt + 2 < NKSTEP) STORESET(a, bufA0, bufB0);
    if (tt + 4 < NKSTEP) LOADSET(a, (tt + 4) * BK);
    COMPUTE(bufA1, bufB1);
    BARRIER();
  }

  // --- epilogue: bias + C store + fused vend (in-register, verified R8) ---
  const int colb = n0 + wn + frow;            // ni=0 column
  const int rowb = m0 + wm + (g << 2);
  const float bv0 = bias[colb];
  const float bv1 = bias[colb + 16];
#pragma unroll
  for (int mi = 0; mi < 4; ++mi) {
#pragma unroll
    for (int r = 0; r < 4; ++r) {
      C[(size_t)(rowb + mi * 16 + r) * NOUT + colb]      = acc[mi][0][r] + bv0;
      C[(size_t)(rowb + mi * 16 + r) * NOUT + colb + 16] = acc[mi][1][r] + bv1;
    }
  }

  {
    const float d0 = decay[colb];
    const float d1 = decay[colb + 16];
    float rr[2][2];  // [chunk half][ni]
#pragma unroll
    for (int ni = 0; ni < 2; ++ni) {
      const float d = ni ? d1 : d0;
      const float bv = ni ? bv1 : bv0;
      const float omd = 1.0f - d;
      const float dd = d * d, d4 = dd * dd, d8 = d4 * d4;
      const float d16 = d8 * d8, d12 = d8 * d4;
      const float dpg = (g == 0) ? d12 : (g == 1) ? d8 : (g == 2) ? d4 : 1.0f;
      float s[4];
#pragma unroll
      for (int mi = 0; mi < 4; ++mi) {
        float v = acc[mi][ni][0] + bv;
        v = v * d + (acc[mi][ni][1] + bv);
        v = v * d + (acc[mi][ni][2] + bv);
        v = v * d + (acc[mi][ni][3] + bv);
        s[mi] = omd * v;
      }
      float ulo = dpg * (s[0] * d16 + s[1]);
      float uhi = dpg * (s[2] * d16 + s[3]);
      ulo += __shfl_xor(ulo, 16); ulo += __shfl_xor(ulo, 32);
      uhi += __shfl_xor(uhi, 16); uhi += __shfl_xor(uhi, 32);
      rr[0][ni] = ulo; rr[1][ni] = uhi;
    }
    const int b     = m0 >> 11;                       // m0 / TT
    const int clo   = ((m0 & (TT - 1)) >> 5) + (wm >> 5);
    const float val = rr[g >> 1][g & 1];
    const int chunk = clo + (g >> 1);
    const int col   = n0 + wn + frow + (g & 1) * 16;
    vend[((size_t)b * NCHUNK + chunk) * NOUT + col] = val;
  }
}

// ---------------------------------------------------------------------------
// Fallback f32 GEMM (verified R1) — only if workspace is too small.
// ---------------------------------------------------------------------------
__global__ __launch_bounds__(256) void gemm_f32_64x64(
    const float* __restrict__ X, const float* __restrict__ W,
    const float* __restrict__ bias, float* __restrict__ C) {
  __shared__ float As[16][65];
  __shared__ float Bs[16][65];
  const int m0  = blockIdx.y * 64;
  const int n0  = blockIdx.x * 64;
  const int tid = threadIdx.x;
  const int tx  = tid & 15;
  const int ty  = tid >> 4;
  const int lr  = tid >> 2;
  const int lk  = (tid & 3) << 2;
  float acc[4][4] = {};
  const float* xa = X + (size_t)(m0 + lr) * KIN + lk;
  const float* wb = W + (size_t)(n0 + lr) * KIN + lk;
  for (int k0 = 0; k0 < KIN; k0 += 16) {
    float4 av = *reinterpret_cast<const float4*>(xa + k0);
    float4 bv = *reinterpret_cast<const float4*>(wb + k0);
    As[lk + 0][lr] = av.x; As[lk + 1][lr] = av.y;
    As[lk + 2][lr] = av.z; As[lk + 3][lr] = av.w;
    Bs[lk + 0][lr] = bv.x; Bs[lk + 1][lr] = bv.y;
    Bs[lk + 2][lr] = bv.z; Bs[lk + 3][lr] = bv.w;
    __syncthreads();
#pragma unroll
    for (int k = 0; k < 16; ++k) {
      float a[4], b[4];
#pragma unroll
      for (int i = 0; i < 4; ++i) a[i] = As[k][ty * 4 + i];
#pragma unroll
      for (int j = 0; j < 4; ++j) b[j] = Bs[k][tx * 4 + j];
#pragma unroll
      for (int i = 0; i < 4; ++i)
#pragma unroll
        for (int j = 0; j < 4; ++j) acc[i][j] += a[i] * b[j];
    }
    __syncthreads();
  }
  const int n = n0 + tx * 4;
  float4 bv = *reinterpret_cast<const float4*>(&bias[n]);
#pragma unroll
  for (int i = 0; i < 4; ++i) {
    const int m = m0 + ty * 4 + i;
    float4 r;
    r.x = acc[i][0] + bv.x; r.y = acc[i][1] + bv.y;
    r.z = acc[i][2] + bv.z; r.w = acc[i][3] + bv.w;
    *reinterpret_cast<float4*>(&C[(size_t)m * NOUT + n]) = r;
  }
}

// ---------------------------------------------------------------------------
// Chunk-carry compose + fixup (verified R3-R8). vend comes from GEMM epilogue.
// ---------------------------------------------------------------------------
__global__ __launch_bounds__(512) void scan_chunks(
    const float* __restrict__ vend, const float* __restrict__ decay,
    float* __restrict__ vinit) {
  const int b = blockIdx.x;
  const int o = threadIdx.x;
  const float d = decay[o];
  float d2 = d * d, d4 = d2 * d2, d8 = d4 * d4, d16 = d8 * d8;
  const float dL = d16 * d16;   // d^CHUNK
  float V = 0.0f;
  for (int c = 0; c < NCHUNK; ++c) {
    const size_t idx = ((size_t)b * NCHUNK + c) * NOUT + o;
    vinit[idx] = V;
    V = dL * V + vend[idx];
  }
}

__global__ __launch_bounds__(512) void scan_fixup(
    float* __restrict__ C, float* __restrict__ states,
    const float* __restrict__ decay, const float* __restrict__ vinit) {
  const int b = blockIdx.x / NCHUNK;
  const int c = blockIdx.x % NCHUNK;
  const int o = threadIdx.x;
  const float d   = decay[o];
  const float omd = 1.0f - d;
  float v = vinit[((size_t)b * NCHUNK + c) * NOUT + o];  // seed = carry-in
  size_t obase = ((size_t)b * TT + (size_t)c * CHUNK) * NOUT + o;
  size_t sbase = ((size_t)b * (TT + 1) + (size_t)c * CHUNK + 1) * NOUT + o;
#pragma unroll 4
  for (int k = 0; k < CHUNK; ++k) {
    v = d * v + omd * C[obase + (size_t)k * NOUT];
    C[obase + (size_t)k * NOUT]      = v;
    states[sbase + (size_t)k * NOUT] = v;
  }
  if (c == 0) states[((size_t)b * (TT + 1)) * NOUT + o] = 0.0f;
}

__global__ __launch_bounds__(512) void scan_seq(
    float* __restrict__ C, float* __restrict__ states,
    const float* __restrict__ decay) {
  const int b = blockIdx.x;
  const int o = threadIdx.x;
  const float d   = decay[o];
  const float omd = 1.0f - d;
  float v = 0.0f;
  states[((size_t)b * (TT + 1)) * NOUT + o] = 0.0f;
  for (int t = 0; t < TT; ++t) {
    const size_t oi = ((size_t)b * TT + t) * NOUT + o;
    float x = C[oi];
    v = d * v + omd * x;
    C[oi] = v;
    states[((size_t)b * (TT + 1) + t + 1) * NOUT + o] = v;
  }
}

extern "C" void kernel_launch(void* const* d_in, const int* in_sizes, int n_in,
                              void* d_out, int out_size, void* d_ws, size_t ws_size,
                              hipStream_t stream) {
  const float* x     = (const float*)d_in[0];  // [B,T,IN]
  const float* w     = (const float*)d_in[1];  // [OUT,IN]
  const float* bias  = (const float*)d_in[2];  // [OUT]
  const float* decay = (const float*)d_in[3];  // [OUT]

  float* out    = (float*)d_out;                 // [B,T,OUT]
  float* states = out + (size_t)BB * TT * NOUT;  // [1,B,T+1,OUT]

  const size_t szW = (size_t)NOUT * KIN;                      // 0.52M elems
  const size_t scan_elems = (size_t)BB * NCHUNK * NOUT;
  const size_t need = szW * sizeof(_Float16)
                    + 2 * scan_elems * sizeof(float);         // ~3 MB

  if (ws_size >= need) {
    _Float16* Wh = (_Float16*)d_ws;
    float* vend  = (float*)(Wh + szW);
    float* vinit = vend + scan_elems;

    conv_f16_kernel<<<256, 256, 0, stream>>>(w, Wh, (int)(szW / 8));
    gemm_f16<<<dim3((BB * TT) / BM, NOUT / BN), 256, 0, stream>>>(
        x, Wh, bias, decay, out, vend);
    scan_chunks<<<BB, NOUT, 0, stream>>>(vend, decay, vinit);
    scan_fixup <<<BB * NCHUNK, NOUT, 0, stream>>>(out, states, decay, vinit);
  } else {
    gemm_f32_64x64<<<dim3(NOUT / 64, (BB * TT) / 64), 256, 0, stream>>>(x, w, bias, out);
    scan_seq<<<BB, NOUT, 0, stream>>>(out, states, decay);
  }
}

// Round 10
// 71.166 us; speedup vs baseline: 2.0048x; 1.0297x over previous
//
#include <hip/hip_runtime.h>
#include <hip/hip_bf16.h>
#include <cstddef>
#include <cstdint>

#define BB    8
#define TT    2048
#define KIN   1024
#define NOUT  512
#define CHUNK 32
#define NCHUNK (TT / CHUNK)   // 64

#define BM 128
#define BN 128
#define BK 32
#define NKSTEP (KIN / BK)     // 32
#define TILEB 8192            // one 128x32 f16 tile = 8KB

typedef __attribute__((ext_vector_type(4))) float          f32x4;
typedef __attribute__((ext_vector_type(4))) unsigned int   u32x4;
typedef _Float16 f16x8 __attribute__((ext_vector_type(8)));

// ---------------------------------------------------------------------------
// f32 [R][1024] -> f16 tiled+preswizzled: tile (r>>7, k>>5) is 8KB contiguous,
// inner layout [row=r&127][slot^((row>>1)&3)]*16B  (== R8's 0-conflict LDS
// image, so the GEMM stages it LINEARLY with global_load_lds).
// Thread: one (row, s8) pair = 32B coalesced read, 16B write.
// ---------------------------------------------------------------------------
__global__ __launch_bounds__(256) void conv_tiled_f16(
    const float* __restrict__ src, unsigned char* __restrict__ dst, int total) {
  int idx = blockIdx.x * blockDim.x + threadIdx.x;
  const int stride = gridDim.x * blockDim.x;
  for (; idx < total; idx += stride) {
    const int r  = idx >> 7;        // global row
    const int s8 = idx & 127;       // 8-element k-slot (16B f16)
    const float* p = src + (size_t)r * KIN + s8 * 8;
    float4 a = *reinterpret_cast<const float4*>(p);
    float4 b = *reinterpret_cast<const float4*>(p + 4);
    f16x8 h;
    h[0] = (_Float16)a.x; h[1] = (_Float16)a.y;
    h[2] = (_Float16)a.z; h[3] = (_Float16)a.w;
    h[4] = (_Float16)b.x; h[5] = (_Float16)b.y;
    h[6] = (_Float16)b.z; h[7] = (_Float16)b.w;
    const int row  = r & 127;
    const int tile = (r >> 7) * NKSTEP + (s8 >> 2);
    const int slot = (s8 & 3) ^ ((row >> 1) & 3);
    *reinterpret_cast<f16x8*>(dst + (size_t)tile * TILEB + row * 64 + slot * 16) = h;
  }
}

#define G2L(gp, sp)                                                        \
  __builtin_amdgcn_global_load_lds(                                       \
      (const __attribute__((address_space(1))) void*)(gp),                \
      (__attribute__((address_space(3))) void*)(sp), 16, 0, 0)

// ---------------------------------------------------------------------------
// fp16 MFMA GEMM — m97 structure: 128x128 tile, BK=32, 4 waves (64x64 each),
// single 16KB LDS buffer, 2-barrier drain K-loop, G2L from CONTIGUOUS
// pre-swizzled tiles (4 linear 4KB bursts/step, zero in-loop VALU prep).
// 16 MFMA per wave-step per 16KB block staging (4x R5's density).
// Epilogue: bias + C store + fused vend chunk-scan (Horner + shfl, R8-verified).
// grid = (128 m, 4 n): linear id = x + 128y, 128%8==0 -> the 4 n-blocks of an
// m-strip share an XCD -> A-tile L2 reuse (verified R3+).
// ---------------------------------------------------------------------------
__global__ __launch_bounds__(256, 2) void gemm_f16(
    const unsigned char* __restrict__ Xt, const unsigned char* __restrict__ Wt,
    const float* __restrict__ bias, const float* __restrict__ decay,
    float* __restrict__ C, float* __restrict__ vend) {
  __shared__ __align__(16) unsigned char smem[2 * TILEB];  // A 8KB | B 8KB

  const int tid  = threadIdx.x;
  const int wave = tid >> 6;
  const int lane = tid & 63;
  const int m0 = blockIdx.x * BM;
  const int n0 = blockIdx.y * BN;
  const int wm = (wave >> 1) * 64;   // 2x2 waves: 64x64 output each
  const int wn = (wave & 1) * 64;
  const int frow = lane & 15;
  const int g    = lane >> 4;

  unsigned char* sA = smem;
  unsigned char* sB = smem + TILEB;

  // per-lane global src (tile image == LDS image, so offset = tid*16)
  const unsigned char* srcA = Xt + (size_t)(m0 >> 7) * NKSTEP * TILEB + tid * 16;
  const unsigned char* srcB = Wt + (size_t)(n0 >> 7) * NKSTEP * TILEB + tid * 16;
  const int ldsw = wave * 1024;

  // fragment-read swizzled k-slot offset (R8-verified ~0 conflicts)
  const int swzr = (g ^ ((frow >> 1) & 3)) << 4;

  f32x4 acc[4][4] = {};

  for (int t = 0; t < NKSTEP; ++t) {
    __syncthreads();                       // prev compute done
    const size_t toff = (size_t)t * TILEB;
    G2L(srcA + toff,        sA + ldsw);
    G2L(srcA + toff + 4096, sA + 4096 + ldsw);
    G2L(srcB + toff,        sB + ldsw);
    G2L(srcB + toff + 4096, sB + 4096 + ldsw);
    __syncthreads();                       // vmcnt drained -> tiles ready

    f16x8 af[4];
#pragma unroll
    for (int mi = 0; mi < 4; ++mi)
      af[mi] = *reinterpret_cast<const f16x8*>(sA + (wm + mi * 16 + frow) * 64 + swzr);
#pragma unroll
    for (int ni = 0; ni < 4; ++ni) {
      f16x8 bf = *reinterpret_cast<const f16x8*>(sB + (wn + ni * 16 + frow) * 64 + swzr);
#pragma unroll
      for (int mi = 0; mi < 4; ++mi)
        acc[mi][ni] = __builtin_amdgcn_mfma_f32_16x16x32_f16(af[mi], bf, acc[mi][ni], 0, 0, 0);
    }
  }

  // --- epilogue: bias + C store ---
  const int colb = n0 + wn + frow;
  const int rowb = m0 + wm + (g << 2);
  float bv[4];
#pragma unroll
  for (int ni = 0; ni < 4; ++ni) bv[ni] = bias[colb + ni * 16];
#pragma unroll
  for (int mi = 0; mi < 4; ++mi) {
#pragma unroll
    for (int r = 0; r < 4; ++r) {
#pragma unroll
      for (int ni = 0; ni < 4; ++ni)
        C[(size_t)(rowb + mi * 16 + r) * NOUT + colb + ni * 16] = acc[mi][ni][r] + bv[ni];
    }
  }

  // --- fused vend: rows wm..wm+63 = 2 chunks of 32; Horner + shfl (R8) ---
  {
    float rlo[4], rhi[4];
#pragma unroll
    for (int ni = 0; ni < 4; ++ni) {
      const float d  = decay[colb + ni * 16];
      const float bb = bv[ni];
      const float omd = 1.0f - d;
      const float dd = d * d, d4 = dd * dd, d8 = d4 * d4;
      const float d16 = d8 * d8, d12 = d8 * d4;
      const float dpg = (g == 0) ? d12 : (g == 1) ? d8 : (g == 2) ? d4 : 1.0f;
      float s[4];
#pragma unroll
      for (int mi = 0; mi < 4; ++mi) {
        float v = acc[mi][ni][0] + bb;
        v = v * d + (acc[mi][ni][1] + bb);
        v = v * d + (acc[mi][ni][2] + bb);
        v = v * d + (acc[mi][ni][3] + bb);
        s[mi] = omd * v;
      }
      float ulo = dpg * (s[0] * d16 + s[1]);
      float uhi = dpg * (s[2] * d16 + s[3]);
      ulo += __shfl_xor(ulo, 16); ulo += __shfl_xor(ulo, 32);
      uhi += __shfl_xor(uhi, 16); uhi += __shfl_xor(uhi, 32);
      rlo[ni] = ulo; rhi[ni] = uhi;
    }
    // lane (g,frow) writes 2 of the 128 values (explicit selects, rule #20)
    const int b   = m0 >> 11;
    const int clo = ((m0 & (TT - 1)) >> 5) + (wm >> 5);
    const int chunk = clo + (g >> 1);
    const int half  = g >> 1;
    const int nia   = g & 1;           // ni for first write
    const float v1 = half ? (nia ? rhi[1] : rhi[0]) : (nia ? rlo[1] : rlo[0]);
    const float v2 = half ? (nia ? rhi[3] : rhi[2]) : (nia ? rlo[3] : rlo[2]);
    const int col1 = n0 + wn + frow + nia * 16;
    float* vp = vend + ((size_t)b * NCHUNK + chunk) * NOUT;
    vp[col1]      = v1;
    vp[col1 + 32] = v2;
  }
}

// ---------------------------------------------------------------------------
// Fallback f32 GEMM (verified R1) — only if workspace is too small.
// ---------------------------------------------------------------------------
__global__ __launch_bounds__(256) void gemm_f32_64x64(
    const float* __restrict__ X, const float* __restrict__ W,
    const float* __restrict__ bias, float* __restrict__ C) {
  __shared__ float As[16][65];
  __shared__ float Bs[16][65];
  const int m0  = blockIdx.y * 64;
  const int n0  = blockIdx.x * 64;
  const int tid = threadIdx.x;
  const int tx  = tid & 15;
  const int ty  = tid >> 4;
  const int lr  = tid >> 2;
  const int lk  = (tid & 3) << 2;
  float acc[4][4] = {};
  const float* xa = X + (size_t)(m0 + lr) * KIN + lk;
  const float* wb = W + (size_t)(n0 + lr) * KIN + lk;
  for (int k0 = 0; k0 < KIN; k0 += 16) {
    float4 av = *reinterpret_cast<const float4*>(xa + k0);
    float4 bv = *reinterpret_cast<const float4*>(wb + k0);
    As[lk + 0][lr] = av.x; As[lk + 1][lr] = av.y;
    As[lk + 2][lr] = av.z; As[lk + 3][lr] = av.w;
    Bs[lk + 0][lr] = bv.x; Bs[lk + 1][lr] = bv.y;
    Bs[lk + 2][lr] = bv.z; Bs[lk + 3][lr] = bv.w;
    __syncthreads();
#pragma unroll
    for (int k = 0; k < 16; ++k) {
      float a[4], b[4];
#pragma unroll
      for (int i = 0; i < 4; ++i) a[i] = As[k][ty * 4 + i];
#pragma unroll
      for (int j = 0; j < 4; ++j) b[j] = Bs[k][tx * 4 + j];
#pragma unroll
      for (int i = 0; i < 4; ++i)
#pragma unroll
        for (int j = 0; j < 4; ++j) acc[i][j] += a[i] * b[j];
    }
    __syncthreads();
  }
  const int n = n0 + tx * 4;
  float4 bv = *reinterpret_cast<const float4*>(&bias[n]);
#pragma unroll
  for (int i = 0; i < 4; ++i) {
    const int m = m0 + ty * 4 + i;
    float4 r;
    r.x = acc[i][0] + bv.x; r.y = acc[i][1] + bv.y;
    r.z = acc[i][2] + bv.z; r.w = acc[i][3] + bv.w;
    *reinterpret_cast<float4*>(&C[(size_t)m * NOUT + n]) = r;
  }
}

// ---------------------------------------------------------------------------
// Chunk-carry compose + fixup (verified R3-R9). vend comes from GEMM epilogue.
// ---------------------------------------------------------------------------
__global__ __launch_bounds__(512) void scan_chunks(
    const float* __restrict__ vend, const float* __restrict__ decay,
    float* __restrict__ vinit) {
  const int b = blockIdx.x;
  const int o = threadIdx.x;
  const float d = decay[o];
  float d2 = d * d, d4 = d2 * d2, d8 = d4 * d4, d16 = d8 * d8;
  const float dL = d16 * d16;   // d^CHUNK
  float V = 0.0f;
  for (int c = 0; c < NCHUNK; ++c) {
    const size_t idx = ((size_t)b * NCHUNK + c) * NOUT + o;
    vinit[idx] = V;
    V = dL * V + vend[idx];
  }
}

__global__ __launch_bounds__(512) void scan_fixup(
    float* __restrict__ C, float* __restrict__ states,
    const float* __restrict__ decay, const float* __restrict__ vinit) {
  const int b = blockIdx.x / NCHUNK;
  const int c = blockIdx.x % NCHUNK;
  const int o = threadIdx.x;
  const float d   = decay[o];
  const float omd = 1.0f - d;
  float v = vinit[((size_t)b * NCHUNK + c) * NOUT + o];  // seed = carry-in
  size_t obase = ((size_t)b * TT + (size_t)c * CHUNK) * NOUT + o;
  size_t sbase = ((size_t)b * (TT + 1) + (size_t)c * CHUNK + 1) * NOUT + o;
#pragma unroll 4
  for (int k = 0; k < CHUNK; ++k) {
    v = d * v + omd * C[obase + (size_t)k * NOUT];
    C[obase + (size_t)k * NOUT]      = v;
    states[sbase + (size_t)k * NOUT] = v;
  }
  if (c == 0) states[((size_t)b * (TT + 1)) * NOUT + o] = 0.0f;
}

__global__ __launch_bounds__(512) void scan_seq(
    float* __restrict__ C, float* __restrict__ states,
    const float* __restrict__ decay) {
  const int b = blockIdx.x;
  const int o = threadIdx.x;
  const float d   = decay[o];
  const float omd = 1.0f - d;
  float v = 0.0f;
  states[((size_t)b * (TT + 1)) * NOUT + o] = 0.0f;
  for (int t = 0; t < TT; ++t) {
    const size_t oi = ((size_t)b * TT + t) * NOUT + o;
    float x = C[oi];
    v = d * v + omd * x;
    C[oi] = v;
    states[((size_t)b * (TT + 1) + t + 1) * NOUT + o] = v;
  }
}

extern "C" void kernel_launch(void* const* d_in, const int* in_sizes, int n_in,
                              void* d_out, int out_size, void* d_ws, size_t ws_size,
                              hipStream_t stream) {
  const float* x     = (const float*)d_in[0];  // [B,T,IN]
  const float* w     = (const float*)d_in[1];  // [OUT,IN]
  const float* bias  = (const float*)d_in[2];  // [OUT]
  const float* decay = (const float*)d_in[3];  // [OUT]

  float* out    = (float*)d_out;                 // [B,T,OUT]
  float* states = out + (size_t)BB * TT * NOUT;  // [1,B,T+1,OUT]

  const size_t szXb = (size_t)BB * TT * KIN * sizeof(_Float16);   // 32 MB
  const size_t szWb = (size_t)NOUT * KIN * sizeof(_Float16);      // 1 MB
  const size_t scan_elems = (size_t)BB * NCHUNK * NOUT;
  const size_t need = szXb + szWb + 2 * scan_elems * sizeof(float);  // ~35 MB

  if (ws_size >= need) {
    unsigned char* Xt = (unsigned char*)d_ws;
    unsigned char* Wt = Xt + szXb;
    float* vend  = (float*)(Wt + szWb);
    float* vinit = vend + scan_elems;

    conv_tiled_f16<<<2048, 256, 0, stream>>>(x, Xt, BB * TT * (KIN / 8));
    conv_tiled_f16<<<256,  256, 0, stream>>>(w, Wt, NOUT * (KIN / 8));
    gemm_f16<<<dim3((BB * TT) / BM, NOUT / BN), 256, 0, stream>>>(
        Xt, Wt, bias, decay, out, vend);
    scan_chunks<<<BB, NOUT, 0, stream>>>(vend, decay, vinit);
    scan_fixup <<<BB * NCHUNK, NOUT, 0, stream>>>(out, states, decay, vinit);
  } else {
    gemm_f32_64x64<<<dim3(NOUT / 64, (BB * TT) / 64), 256, 0, stream>>>(x, w, bias, out);
    scan_seq<<<BB, NOUT, 0, stream>>>(out, states, decay);
  }
}

// Round 11
// 69.602 us; speedup vs baseline: 2.0499x; 1.0225x over previous
//
#include <hip/hip_runtime.h>
#include <hip/hip_bf16.h>
#include <cstddef>
#include <cstdint>

#define BB    8
#define TT    2048
#define KIN   1024
#define NOUT  512
#define CHUNK 32
#define NCHUNK (TT / CHUNK)   // 64

#define BM 128
#define BN 128
#define BK 64
#define NKSTEP (KIN / BK)     // 16
#define NPAGE  (KIN / 32)     // 32 8KB pages per 128-row strip
#define TILEB 8192            // one 128x32 f16 page = 8KB

typedef __attribute__((ext_vector_type(4))) float          f32x4;
typedef __attribute__((ext_vector_type(4))) unsigned int   u32x4;
typedef _Float16 f16x8 __attribute__((ext_vector_type(8)));

// ---------------------------------------------------------------------------
// f32 [R][1024] -> f16 tiled+preswizzled pages (verified R10): page
// (r>>7, k>>5) is 8KB contiguous, inner layout [row][slot^((row>>1)&3)]*16B
// == the 0-conflict LDS image, so the GEMM stages it LINEARLY via G2L.
// ---------------------------------------------------------------------------
__global__ __launch_bounds__(256) void conv_tiled_f16(
    const float* __restrict__ src, unsigned char* __restrict__ dst, int total) {
  int idx = blockIdx.x * blockDim.x + threadIdx.x;
  const int stride = gridDim.x * blockDim.x;
  for (; idx < total; idx += stride) {
    const int r  = idx >> 7;        // global row
    const int s8 = idx & 127;       // 8-element k-slot (16B f16)
    const float* p = src + (size_t)r * KIN + s8 * 8;
    float4 a = *reinterpret_cast<const float4*>(p);
    float4 b = *reinterpret_cast<const float4*>(p + 4);
    f16x8 h;
    h[0] = (_Float16)a.x; h[1] = (_Float16)a.y;
    h[2] = (_Float16)a.z; h[3] = (_Float16)a.w;
    h[4] = (_Float16)b.x; h[5] = (_Float16)b.y;
    h[6] = (_Float16)b.z; h[7] = (_Float16)b.w;
    const int row  = r & 127;
    const int page = (r >> 7) * NPAGE + (s8 >> 2);
    const int slot = (s8 & 3) ^ ((row >> 1) & 3);
    *reinterpret_cast<f16x8*>(dst + (size_t)page * TILEB + row * 64 + slot * 16) = h;
  }
}

#define G2L(gp, sp)                                                        \
  __builtin_amdgcn_global_load_lds(                                       \
      (const __attribute__((address_space(1))) void*)(gp),                \
      (__attribute__((address_space(3))) void*)(sp), 16, 0, 0)

// ---------------------------------------------------------------------------
// fp16 MFMA GEMM — m97 structure, BK=64: 128x128 tile, 4 waves (64x64 each),
// 32KB LDS (A 16KB | B 16KB), 16 K-steps, 2-barrier drain loop, 8 linear G2L
// per step from contiguous pre-swizzled pages, 32 MFMA per wave-step.
// C stored as f16 to workspace (half write traffic); fixup re-reads it.
// Epilogue: fused vend chunk-scan (Horner + shfl, R8/R10-verified).
// grid = (128 m, 4 n): linear id = x + 128y, 128%8==0 -> the 4 n-blocks of an
// m-strip share an XCD -> A-page L2 reuse (verified R3+).
// ---------------------------------------------------------------------------
__global__ __launch_bounds__(256, 2) void gemm_f16(
    const unsigned char* __restrict__ Xt, const unsigned char* __restrict__ Wt,
    const float* __restrict__ bias, const float* __restrict__ decay,
    unsigned short* __restrict__ Cws, float* __restrict__ vend) {
  __shared__ __align__(16) unsigned char smem[2 * 16384];  // A 16KB | B 16KB

  const int tid  = threadIdx.x;
  const int wave = tid >> 6;
  const int lane = tid & 63;
  const int m0 = blockIdx.x * BM;
  const int n0 = blockIdx.y * BN;
  const int wm = (wave >> 1) * 64;   // 2x2 waves: 64x64 output each
  const int wn = (wave & 1) * 64;
  const int frow = lane & 15;
  const int g    = lane >> 4;

  unsigned char* sA = smem;
  unsigned char* sB = smem + 16384;

  // per-lane global src (page image == LDS image, so offset = tid*16)
  const unsigned char* srcA = Xt + (size_t)(m0 >> 7) * NPAGE * TILEB + tid * 16;
  const unsigned char* srcB = Wt + (size_t)(n0 >> 7) * NPAGE * TILEB + tid * 16;
  const int ldsw = wave * 1024;

  // fragment-read swizzled k-slot offset (R8/R10-verified ~0 conflicts)
  const int swzr = (g ^ ((frow >> 1) & 3)) << 4;

  f32x4 acc[4][4] = {};

  for (int t = 0; t < NKSTEP; ++t) {
    __syncthreads();                       // prev compute done
    const size_t toff = (size_t)(2 * t) * TILEB;   // two contiguous pages
#pragma unroll
    for (int q = 0; q < 4; ++q) {
      G2L(srcA + toff + q * 4096, sA + q * 4096 + ldsw);
      G2L(srcB + toff + q * 4096, sB + q * 4096 + ldsw);
    }
    __syncthreads();                       // vmcnt drained -> tiles ready

#pragma unroll
    for (int kk = 0; kk < 2; ++kk) {
      f16x8 af[4];
#pragma unroll
      for (int mi = 0; mi < 4; ++mi)
        af[mi] = *reinterpret_cast<const f16x8*>(
            sA + kk * 8192 + (wm + mi * 16 + frow) * 64 + swzr);
#pragma unroll
      for (int ni = 0; ni < 4; ++ni) {
        f16x8 bf = *reinterpret_cast<const f16x8*>(
            sB + kk * 8192 + (wn + ni * 16 + frow) * 64 + swzr);
#pragma unroll
        for (int mi = 0; mi < 4; ++mi)
          acc[mi][ni] = __builtin_amdgcn_mfma_f32_16x16x32_f16(af[mi], bf, acc[mi][ni], 0, 0, 0);
      }
    }
  }

  // --- epilogue: bias + f16 C store to workspace ---
  const int colb = n0 + wn + frow;
  const int rowb = m0 + wm + (g << 2);
  float bv[4];
#pragma unroll
  for (int ni = 0; ni < 4; ++ni) bv[ni] = bias[colb + ni * 16];
#pragma unroll
  for (int mi = 0; mi < 4; ++mi) {
#pragma unroll
    for (int r = 0; r < 4; ++r) {
#pragma unroll
      for (int ni = 0; ni < 4; ++ni) {
        const _Float16 hv = (_Float16)(acc[mi][ni][r] + bv[ni]);
        Cws[(size_t)(rowb + mi * 16 + r) * NOUT + colb + ni * 16] =
            __builtin_bit_cast(unsigned short, hv);
      }
    }
  }

  // --- fused vend: rows wm..wm+63 = 2 chunks of 32; Horner + shfl (R8/R10) ---
  {
    float rlo[4], rhi[4];
#pragma unroll
    for (int ni = 0; ni < 4; ++ni) {
      const float d  = decay[colb + ni * 16];
      const float bb = bv[ni];
      const float omd = 1.0f - d;
      const float dd = d * d, d4 = dd * dd, d8 = d4 * d4;
      const float d16 = d8 * d8, d12 = d8 * d4;
      const float dpg = (g == 0) ? d12 : (g == 1) ? d8 : (g == 2) ? d4 : 1.0f;
      float s[4];
#pragma unroll
      for (int mi = 0; mi < 4; ++mi) {
        float v = acc[mi][ni][0] + bb;
        v = v * d + (acc[mi][ni][1] + bb);
        v = v * d + (acc[mi][ni][2] + bb);
        v = v * d + (acc[mi][ni][3] + bb);
        s[mi] = omd * v;
      }
      float ulo = dpg * (s[0] * d16 + s[1]);
      float uhi = dpg * (s[2] * d16 + s[3]);
      ulo += __shfl_xor(ulo, 16); ulo += __shfl_xor(ulo, 32);
      uhi += __shfl_xor(uhi, 16); uhi += __shfl_xor(uhi, 32);
      rlo[ni] = ulo; rhi[ni] = uhi;
    }
    const int b   = m0 >> 11;
    const int clo = ((m0 & (TT - 1)) >> 5) + (wm >> 5);
    const int chunk = clo + (g >> 1);
    const int half  = g >> 1;
    const int nia   = g & 1;
    const float v1 = half ? (nia ? rhi[1] : rhi[0]) : (nia ? rlo[1] : rlo[0]);
    const float v2 = half ? (nia ? rhi[3] : rhi[2]) : (nia ? rlo[3] : rlo[2]);
    const int col1 = n0 + wn + frow + nia * 16;
    float* vp = vend + ((size_t)b * NCHUNK + chunk) * NOUT;
    vp[col1]      = v1;
    vp[col1 + 32] = v2;
  }
}

// ---------------------------------------------------------------------------
// Fallback f32 GEMM (verified R1) — only if workspace is too small.
// ---------------------------------------------------------------------------
__global__ __launch_bounds__(256) void gemm_f32_64x64(
    const float* __restrict__ X, const float* __restrict__ W,
    const float* __restrict__ bias, float* __restrict__ C) {
  __shared__ float As[16][65];
  __shared__ float Bs[16][65];
  const int m0  = blockIdx.y * 64;
  const int n0  = blockIdx.x * 64;
  const int tid = threadIdx.x;
  const int tx  = tid & 15;
  const int ty  = tid >> 4;
  const int lr  = tid >> 2;
  const int lk  = (tid & 3) << 2;
  float acc[4][4] = {};
  const float* xa = X + (size_t)(m0 + lr) * KIN + lk;
  const float* wb = W + (size_t)(n0 + lr) * KIN + lk;
  for (int k0 = 0; k0 < KIN; k0 += 16) {
    float4 av = *reinterpret_cast<const float4*>(xa + k0);
    float4 bv = *reinterpret_cast<const float4*>(wb + k0);
    As[lk + 0][lr] = av.x; As[lk + 1][lr] = av.y;
    As[lk + 2][lr] = av.z; As[lk + 3][lr] = av.w;
    Bs[lk + 0][lr] = bv.x; Bs[lk + 1][lr] = bv.y;
    Bs[lk + 2][lr] = bv.z; Bs[lk + 3][lr] = bv.w;
    __syncthreads();
#pragma unroll
    for (int k = 0; k < 16; ++k) {
      float a[4], b[4];
#pragma unroll
      for (int i = 0; i < 4; ++i) a[i] = As[k][ty * 4 + i];
#pragma unroll
      for (int j = 0; j < 4; ++j) b[j] = Bs[k][tx * 4 + j];
#pragma unroll
      for (int i = 0; i < 4; ++i)
#pragma unroll
        for (int j = 0; j < 4; ++j) acc[i][j] += a[i] * b[j];
    }
    __syncthreads();
  }
  const int n = n0 + tx * 4;
  float4 bv = *reinterpret_cast<const float4*>(&bias[n]);
#pragma unroll
  for (int i = 0; i < 4; ++i) {
    const int m = m0 + ty * 4 + i;
    float4 r;
    r.x = acc[i][0] + bv.x; r.y = acc[i][1] + bv.y;
    r.z = acc[i][2] + bv.z; r.w = acc[i][3] + bv.w;
    *reinterpret_cast<float4*>(&C[(size_t)m * NOUT + n]) = r;
  }
}

// ---------------------------------------------------------------------------
// Fixup with integrated chunk-carry compose: block (b,c) first composes its
// own vinit from vend (<=63 fmas over L2-hot 2MB), then scans its chunk
// reading f16 current from ws and writing outputs + states (the only d_out
// writer).  Verified scan math R3-R10.
// ---------------------------------------------------------------------------
__global__ __launch_bounds__(512) void scan_fixup2(
    const unsigned short* __restrict__ Cws, const float* __restrict__ vend,
    const float* __restrict__ decay, float* __restrict__ out,
    float* __restrict__ states) {
  const int b = blockIdx.x / NCHUNK;
  const int c = blockIdx.x % NCHUNK;
  const int o = threadIdx.x;
  const float d   = decay[o];
  const float omd = 1.0f - d;
  const float dd = d * d, d4 = dd * dd, d8 = d4 * d4, d16 = d8 * d8;
  const float dL = d16 * d16;   // d^CHUNK

  // compose carry-in for this chunk from vend[0..c)
  float v = 0.0f;
  const float* vp = vend + (size_t)b * NCHUNK * NOUT + o;
  for (int cc = 0; cc < c; ++cc) v = dL * v + vp[(size_t)cc * NOUT];

  size_t obase = ((size_t)b * TT + (size_t)c * CHUNK) * NOUT + o;
  size_t sbase = ((size_t)b * (TT + 1) + (size_t)c * CHUNK + 1) * NOUT + o;
#pragma unroll 4
  for (int k = 0; k < CHUNK; ++k) {
    const unsigned short hu = Cws[obase + (size_t)k * NOUT];
    const float cur = (float)__builtin_bit_cast(_Float16, hu);
    v = d * v + omd * cur;
    out[obase + (size_t)k * NOUT]    = v;
    states[sbase + (size_t)k * NOUT] = v;
  }
  if (c == 0) states[((size_t)b * (TT + 1)) * NOUT + o] = 0.0f;
}

__global__ __launch_bounds__(512) void scan_seq(
    float* __restrict__ C, float* __restrict__ states,
    const float* __restrict__ decay) {
  const int b = blockIdx.x;
  const int o = threadIdx.x;
  const float d   = decay[o];
  const float omd = 1.0f - d;
  float v = 0.0f;
  states[((size_t)b * (TT + 1)) * NOUT + o] = 0.0f;
  for (int t = 0; t < TT; ++t) {
    const size_t oi = ((size_t)b * TT + t) * NOUT + o;
    float x = C[oi];
    v = d * v + omd * x;
    C[oi] = v;
    states[((size_t)b * (TT + 1) + t + 1) * NOUT + o] = v;
  }
}

extern "C" void kernel_launch(void* const* d_in, const int* in_sizes, int n_in,
                              void* d_out, int out_size, void* d_ws, size_t ws_size,
                              hipStream_t stream) {
  const float* x     = (const float*)d_in[0];  // [B,T,IN]
  const float* w     = (const float*)d_in[1];  // [OUT,IN]
  const float* bias  = (const float*)d_in[2];  // [OUT]
  const float* decay = (const float*)d_in[3];  // [OUT]

  float* out    = (float*)d_out;                 // [B,T,OUT]
  float* states = out + (size_t)BB * TT * NOUT;  // [1,B,T+1,OUT]

  const size_t szXb = (size_t)BB * TT * KIN * sizeof(_Float16);     // 32 MB
  const size_t szWb = (size_t)NOUT * KIN * sizeof(_Float16);        // 1 MB
  const size_t szCb = (size_t)BB * TT * NOUT * sizeof(_Float16);    // 16.8 MB
  const size_t scan_elems = (size_t)BB * NCHUNK * NOUT;
  const size_t need = szXb + szWb + szCb + scan_elems * sizeof(float);  // ~52 MB

  if (ws_size >= need) {
    unsigned char*  Xt  = (unsigned char*)d_ws;
    unsigned char*  Wt  = Xt + szXb;
    unsigned short* Cws = (unsigned short*)(Wt + szWb);
    float*          vend = (float*)(Cws + (size_t)BB * TT * NOUT);

    conv_tiled_f16<<<2048, 256, 0, stream>>>(x, Xt, BB * TT * (KIN / 8));
    conv_tiled_f16<<<256,  256, 0, stream>>>(w, Wt, NOUT * (KIN / 8));
    gemm_f16<<<dim3((BB * TT) / BM, NOUT / BN), 256, 0, stream>>>(
        Xt, Wt, bias, decay, Cws, vend);
    scan_fixup2<<<BB * NCHUNK, NOUT, 0, stream>>>(Cws, vend, decay, out, states);
  } else {
    gemm_f32_64x64<<<dim3(NOUT / 64, (BB * TT) / 64), 256, 0, stream>>>(x, w, bias, out);
    scan_seq<<<BB, NOUT, 0, stream>>>(out, states, decay);
  }
}

// Round 12
// 62.158 us; speedup vs baseline: 2.2954x; 1.1198x over previous
//
#include <hip/hip_runtime.h>
#include <hip/hip_bf16.h>
#include <cstddef>
#include <cstdint>

#define BB    8
#define TT    2048
#define KIN   1024
#define NOUT  512
#define CHUNK 32
#define NCHUNK (TT / CHUNK)   // 64

#define BM 128
#define BN 128
#define BK 64
#define NKSTEP (KIN / BK)     // 16
#define NPAGE  (KIN / 32)     // 32 8KB pages per 128-row strip (W only)
#define TILEB 8192            // one 128x32 f16 page = 8KB

typedef __attribute__((ext_vector_type(4))) float          f32x4;
typedef __attribute__((ext_vector_type(4))) unsigned int   u32x4;
typedef _Float16 f16x8 __attribute__((ext_vector_type(8)));

// ---------------------------------------------------------------------------
// W f32 [R][1024] -> f16 tiled+preswizzled pages (verified R10/R11): page
// (r>>7, k>>5) is 8KB contiguous, inner [row][slot^((row>>1)&3)]*16B == the
// 0-conflict LDS image, so the GEMM stages it LINEARLY via G2L.  W only (1MB).
// ---------------------------------------------------------------------------
__global__ __launch_bounds__(256) void conv_tiled_f16(
    const float* __restrict__ src, unsigned char* __restrict__ dst, int total) {
  int idx = blockIdx.x * blockDim.x + threadIdx.x;
  const int stride = gridDim.x * blockDim.x;
  for (; idx < total; idx += stride) {
    const int r  = idx >> 7;        // global row
    const int s8 = idx & 127;       // 8-element k-slot (16B f16)
    const float* p = src + (size_t)r * KIN + s8 * 8;
    float4 a = *reinterpret_cast<const float4*>(p);
    float4 b = *reinterpret_cast<const float4*>(p + 4);
    f16x8 h;
    h[0] = (_Float16)a.x; h[1] = (_Float16)a.y;
    h[2] = (_Float16)a.z; h[3] = (_Float16)a.w;
    h[4] = (_Float16)b.x; h[5] = (_Float16)b.y;
    h[6] = (_Float16)b.z; h[7] = (_Float16)b.w;
    const int row  = r & 127;
    const int page = (r >> 7) * NPAGE + (s8 >> 2);
    const int slot = (s8 & 3) ^ ((row >> 1) & 3);
    *reinterpret_cast<f16x8*>(dst + (size_t)page * TILEB + row * 64 + slot * 16) = h;
  }
}

#define G2L(gp, sp)                                                        \
  __builtin_amdgcn_global_load_lds(                                       \
      (const __attribute__((address_space(1))) void*)(gp),                \
      (__attribute__((address_space(3))) void*)(sp), 16, 0, 0)

// ---------------------------------------------------------------------------
// fp16 MFMA GEMM, X read DIRECTLY as f32 (no conv_x pass):
//  - A: raw f32 X staged via G2L, per-lane inverse-swizzled source
//    (slot^ (row&7), rule #21), LDS linear [row][slot] rows of 256B.
//    Fragments read as 2x f32x4 at slots (kk*8+g*2+{0,1})^(row&7): 16 lanes
//    hit 8 XOR-distinct slots = 2-way bank alias = free.  cvt_pkrtz -> f16.
//  - B: pre-converted f16 pages, linear G2L, swzr read (R10/R11-verified).
//  - m97 drain loop: BK=64, 16 steps, 12 G2L/step, 32 MFMA/wave-step,
//    LDS 48KB single-buffered, 2 barriers/step.
//  - C stored f16 to workspace; epilogue fuses vend scan (R8-R11-verified).
// grid = (128 m, 4 n): 128%8==0 -> an m-strip's n-blocks share an XCD.
// ---------------------------------------------------------------------------
__global__ __launch_bounds__(256, 2) void gemm_f16(
    const float* __restrict__ X, const unsigned char* __restrict__ Wt,
    const float* __restrict__ bias, const float* __restrict__ decay,
    unsigned short* __restrict__ Cws, float* __restrict__ vend) {
  __shared__ __align__(16) unsigned char smem[32768 + 16384];  // A f32 | B f16

  const int tid  = threadIdx.x;
  const int wave = tid >> 6;
  const int lane = tid & 63;
  const int m0 = blockIdx.x * BM;
  const int n0 = blockIdx.y * BN;
  const int wm = (wave >> 1) * 64;   // 2x2 waves: 64x64 output each
  const int wn = (wave & 1) * 64;
  const int frow = lane & 15;
  const int g    = lane >> 4;

  unsigned char* sA = smem;
  unsigned char* sB = smem + 32768;

  // --- A staging: issue q covers rows q*16..q*16+15; this lane handles
  // row rA = q*16 + wave*4 + (lane>>4), linear slot (lane&15), source slot
  // swizzled so LDS[row][slot] = X[row][slot^(row&7)] (16B f32 slots). ---
  const int arow4 = wave * 4 + (lane >> 4);          // row offset within issue
  const int aslot = lane & 15;
  // per-issue row parity differs only via q*16 (multiple of 16) -> (row&7)
  // depends only on arow4&7
  const float* gA = X + (size_t)(m0 + arow4) * KIN + ((aslot ^ (arow4 & 7)) << 2);
  const int ldsw = wave * 1024;                      // wave-linear slice

  // --- B staging via linear G2L from pages (page image == LDS image) ---
  const unsigned char* srcB = Wt + (size_t)(n0 >> 7) * NPAGE * TILEB + tid * 16;

  // --- fragment-read offsets ---
  const int arswz = frow & 7;                        // A row swizzle key
  const int swzr  = (g ^ ((frow >> 1) & 3)) << 4;    // B k-slot offset (R8)

  f32x4 acc[4][4] = {};

  for (int t = 0; t < NKSTEP; ++t) {
    __syncthreads();                       // prev compute done
    const int k0 = t * BK;
#pragma unroll
    for (int q = 0; q < 8; ++q)            // A: 8 issues x 16 rows x 256B
      G2L(gA + (size_t)(q * 16) * KIN + k0, sA + q * 4096 + ldsw);
    const size_t boff = (size_t)(2 * t) * TILEB;
#pragma unroll
    for (int q = 0; q < 4; ++q)            // B: 2 contiguous 8KB pages
      G2L(srcB + boff + q * 4096, sB + q * 4096 + ldsw);
    __syncthreads();                       // vmcnt drained -> tiles ready

#pragma unroll
    for (int kk = 0; kk < 2; ++kk) {
      f16x8 af[4];
#pragma unroll
      for (int mi = 0; mi < 4; ++mi) {
        const int row = wm + mi * 16 + frow;
        const unsigned char* ap = sA + row * 256;
        const int ks0 = kk * 8 + g * 2;
        f32x4 q0 = *reinterpret_cast<const f32x4*>(ap + ((ks0    ) ^ arswz) * 16);
        f32x4 q1 = *reinterpret_cast<const f32x4*>(ap + ((ks0 + 1) ^ arswz) * 16);
        u32x4 hv;
        hv[0] = __builtin_bit_cast(unsigned int, __builtin_amdgcn_cvt_pkrtz(q0[0], q0[1]));
        hv[1] = __builtin_bit_cast(unsigned int, __builtin_amdgcn_cvt_pkrtz(q0[2], q0[3]));
        hv[2] = __builtin_bit_cast(unsigned int, __builtin_amdgcn_cvt_pkrtz(q1[0], q1[1]));
        hv[3] = __builtin_bit_cast(unsigned int, __builtin_amdgcn_cvt_pkrtz(q1[2], q1[3]));
        af[mi] = __builtin_bit_cast(f16x8, hv);
      }
#pragma unroll
      for (int ni = 0; ni < 4; ++ni) {
        f16x8 bf = *reinterpret_cast<const f16x8*>(
            sB + kk * 8192 + (wn + ni * 16 + frow) * 64 + swzr);
#pragma unroll
        for (int mi = 0; mi < 4; ++mi)
          acc[mi][ni] = __builtin_amdgcn_mfma_f32_16x16x32_f16(af[mi], bf, acc[mi][ni], 0, 0, 0);
      }
    }
  }

  // --- epilogue: bias + f16 C store to workspace (verified R11) ---
  const int colb = n0 + wn + frow;
  const int rowb = m0 + wm + (g << 2);
  float bv[4];
#pragma unroll
  for (int ni = 0; ni < 4; ++ni) bv[ni] = bias[colb + ni * 16];
#pragma unroll
  for (int mi = 0; mi < 4; ++mi) {
#pragma unroll
    for (int r = 0; r < 4; ++r) {
#pragma unroll
      for (int ni = 0; ni < 4; ++ni) {
        const _Float16 hv = (_Float16)(acc[mi][ni][r] + bv[ni]);
        Cws[(size_t)(rowb + mi * 16 + r) * NOUT + colb + ni * 16] =
            __builtin_bit_cast(unsigned short, hv);
      }
    }
  }

  // --- fused vend: Horner + shfl (verified R8/R10/R11) ---
  {
    float rlo[4], rhi[4];
#pragma unroll
    for (int ni = 0; ni < 4; ++ni) {
      const float d  = decay[colb + ni * 16];
      const float bb = bv[ni];
      const float omd = 1.0f - d;
      const float dd = d * d, d4 = dd * dd, d8 = d4 * d4;
      const float d16 = d8 * d8, d12 = d8 * d4;
      const float dpg = (g == 0) ? d12 : (g == 1) ? d8 : (g == 2) ? d4 : 1.0f;
      float s[4];
#pragma unroll
      for (int mi = 0; mi < 4; ++mi) {
        float v = acc[mi][ni][0] + bb;
        v = v * d + (acc[mi][ni][1] + bb);
        v = v * d + (acc[mi][ni][2] + bb);
        v = v * d + (acc[mi][ni][3] + bb);
        s[mi] = omd * v;
      }
      float ulo = dpg * (s[0] * d16 + s[1]);
      float uhi = dpg * (s[2] * d16 + s[3]);
      ulo += __shfl_xor(ulo, 16); ulo += __shfl_xor(ulo, 32);
      uhi += __shfl_xor(uhi, 16); uhi += __shfl_xor(uhi, 32);
      rlo[ni] = ulo; rhi[ni] = uhi;
    }
    const int b   = m0 >> 11;
    const int clo = ((m0 & (TT - 1)) >> 5) + (wm >> 5);
    const int chunk = clo + (g >> 1);
    const int half  = g >> 1;
    const int nia   = g & 1;
    const float v1 = half ? (nia ? rhi[1] : rhi[0]) : (nia ? rlo[1] : rlo[0]);
    const float v2 = half ? (nia ? rhi[3] : rhi[2]) : (nia ? rlo[3] : rlo[2]);
    const int col1 = n0 + wn + frow + nia * 16;
    float* vp = vend + ((size_t)b * NCHUNK + chunk) * NOUT;
    vp[col1]      = v1;
    vp[col1 + 32] = v2;
  }
}

// ---------------------------------------------------------------------------
// Fallback f32 GEMM (verified R1) — only if workspace is too small.
// ---------------------------------------------------------------------------
__global__ __launch_bounds__(256) void gemm_f32_64x64(
    const float* __restrict__ X, const float* __restrict__ W,
    const float* __restrict__ bias, float* __restrict__ C) {
  __shared__ float As[16][65];
  __shared__ float Bs[16][65];
  const int m0  = blockIdx.y * 64;
  const int n0  = blockIdx.x * 64;
  const int tid = threadIdx.x;
  const int tx  = tid & 15;
  const int ty  = tid >> 4;
  const int lr  = tid >> 2;
  const int lk  = (tid & 3) << 2;
  float acc[4][4] = {};
  const float* xa = X + (size_t)(m0 + lr) * KIN + lk;
  const float* wb = W + (size_t)(n0 + lr) * KIN + lk;
  for (int k0 = 0; k0 < KIN; k0 += 16) {
    float4 av = *reinterpret_cast<const float4*>(xa + k0);
    float4 bv = *reinterpret_cast<const float4*>(wb + k0);
    As[lk + 0][lr] = av.x; As[lk + 1][lr] = av.y;
    As[lk + 2][lr] = av.z; As[lk + 3][lr] = av.w;
    Bs[lk + 0][lr] = bv.x; Bs[lk + 1][lr] = bv.y;
    Bs[lk + 2][lr] = bv.z; Bs[lk + 3][lr] = bv.w;
    __syncthreads();
#pragma unroll
    for (int k = 0; k < 16; ++k) {
      float a[4], b[4];
#pragma unroll
      for (int i = 0; i < 4; ++i) a[i] = As[k][ty * 4 + i];
#pragma unroll
      for (int j = 0; j < 4; ++j) b[j] = Bs[k][tx * 4 + j];
#pragma unroll
      for (int i = 0; i < 4; ++i)
#pragma unroll
        for (int j = 0; j < 4; ++j) acc[i][j] += a[i] * b[j];
    }
    __syncthreads();
  }
  const int n = n0 + tx * 4;
  float4 bv = *reinterpret_cast<const float4*>(&bias[n]);
#pragma unroll
  for (int i = 0; i < 4; ++i) {
    const int m = m0 + ty * 4 + i;
    float4 r;
    r.x = acc[i][0] + bv.x; r.y = acc[i][1] + bv.y;
    r.z = acc[i][2] + bv.z; r.w = acc[i][3] + bv.w;
    *reinterpret_cast<float4*>(&C[(size_t)m * NOUT + n]) = r;
  }
}

// ---------------------------------------------------------------------------
// Fixup with integrated chunk-carry compose (verified R11): block (b,c)
// composes vinit from vend, scans its chunk from f16 Cws, writes out+states.
// ---------------------------------------------------------------------------
__global__ __launch_bounds__(512) void scan_fixup2(
    const unsigned short* __restrict__ Cws, const float* __restrict__ vend,
    const float* __restrict__ decay, float* __restrict__ out,
    float* __restrict__ states) {
  const int b = blockIdx.x / NCHUNK;
  const int c = blockIdx.x % NCHUNK;
  const int o = threadIdx.x;
  const float d   = decay[o];
  const float omd = 1.0f - d;
  const float dd = d * d, d4 = dd * dd, d8 = d4 * d4, d16 = d8 * d8;
  const float dL = d16 * d16;   // d^CHUNK

  float v = 0.0f;
  const float* vp = vend + (size_t)b * NCHUNK * NOUT + o;
  for (int cc = 0; cc < c; ++cc) v = dL * v + vp[(size_t)cc * NOUT];

  size_t obase = ((size_t)b * TT + (size_t)c * CHUNK) * NOUT + o;
  size_t sbase = ((size_t)b * (TT + 1) + (size_t)c * CHUNK + 1) * NOUT + o;
#pragma unroll 4
  for (int k = 0; k < CHUNK; ++k) {
    const unsigned short hu = Cws[obase + (size_t)k * NOUT];
    const float cur = (float)__builtin_bit_cast(_Float16, hu);
    v = d * v + omd * cur;
    out[obase + (size_t)k * NOUT]    = v;
    states[sbase + (size_t)k * NOUT] = v;
  }
  if (c == 0) states[((size_t)b * (TT + 1)) * NOUT + o] = 0.0f;
}

__global__ __launch_bounds__(512) void scan_seq(
    float* __restrict__ C, float* __restrict__ states,
    const float* __restrict__ decay) {
  const int b = blockIdx.x;
  const int o = threadIdx.x;
  const float d   = decay[o];
  const float omd = 1.0f - d;
  float v = 0.0f;
  states[((size_t)b * (TT + 1)) * NOUT + o] = 0.0f;
  for (int t = 0; t < TT; ++t) {
    const size_t oi = ((size_t)b * TT + t) * NOUT + o;
    float x = C[oi];
    v = d * v + omd * x;
    C[oi] = v;
    states[((size_t)b * (TT + 1) + t + 1) * NOUT + o] = v;
  }
}

extern "C" void kernel_launch(void* const* d_in, const int* in_sizes, int n_in,
                              void* d_out, int out_size, void* d_ws, size_t ws_size,
                              hipStream_t stream) {
  const float* x     = (const float*)d_in[0];  // [B,T,IN]
  const float* w     = (const float*)d_in[1];  // [OUT,IN]
  const float* bias  = (const float*)d_in[2];  // [OUT]
  const float* decay = (const float*)d_in[3];  // [OUT]

  float* out    = (float*)d_out;                 // [B,T,OUT]
  float* states = out + (size_t)BB * TT * NOUT;  // [1,B,T+1,OUT]

  const size_t szWb = (size_t)NOUT * KIN * sizeof(_Float16);        // 1 MB
  const size_t szCb = (size_t)BB * TT * NOUT * sizeof(_Float16);    // 16.8 MB
  const size_t scan_elems = (size_t)BB * NCHUNK * NOUT;
  const size_t need = szWb + szCb + scan_elems * sizeof(float);     // ~20 MB

  if (ws_size >= need) {
    unsigned char*  Wt   = (unsigned char*)d_ws;
    unsigned short* Cws  = (unsigned short*)(Wt + szWb);
    float*          vend = (float*)(Cws + (size_t)BB * TT * NOUT);

    conv_tiled_f16<<<256, 256, 0, stream>>>(w, Wt, NOUT * (KIN / 8));
    gemm_f16<<<dim3((BB * TT) / BM, NOUT / BN), 256, 0, stream>>>(
        x, Wt, bias, decay, Cws, vend);
    scan_fixup2<<<BB * NCHUNK, NOUT, 0, stream>>>(Cws, vend, decay, out, states);
  } else {
    gemm_f32_64x64<<<dim3(NOUT / 64, (BB * TT) / 64), 256, 0, stream>>>(x, w, bias, out);
    scan_seq<<<BB, NOUT, 0, stream>>>(out, states, decay);
  }
}